// Round 8
// baseline (1034.702 us; speedup 1.0000x reference)
//
#include <hip/hip_runtime.h>
#include <math.h>

#define NN   13
#define HH   128
#define NL   8
#define NJ   17
#define OBSD 348
#define DMAX 33
#define TB   16
#define NTHR 1024
#define ASTRIDE 256   // shorts per A row = 512 B; bank-conflict-free via unit swizzle
#define HSTRIDE 128   // same row viewed as fp32

// FEAT_IDX table (13 x 33), pad = -1
__constant__ int c_feat[NN * DMAX] = {
  0,1,2,3,4,22,23,24,25,26,27,45,46,47,48,49,50,51,52,53,54,175,176,177,178,179,180,270,271,272,273,274,275,
  5,6,28,29,55,56,57,58,59,60,61,62,63,64,181,182,183,184,185,186,276,277,278,279,280,281,-1,-1,-1,-1,-1,-1,-1,
  7,30,65,66,67,68,69,70,71,72,73,74,187,188,189,190,191,192,253,254,255,282,283,284,285,286,287,-1,-1,-1,-1,-1,-1,
  8,9,10,11,31,32,33,34,75,76,77,78,79,80,81,82,83,84,193,194,195,196,197,198,256,257,258,288,289,290,291,292,293,
  11,34,85,86,87,88,89,90,91,92,93,94,199,200,201,202,203,204,259,294,295,296,297,298,299,-1,-1,-1,-1,-1,-1,-1,-1,
  95,96,97,98,99,100,101,102,103,104,205,206,207,208,209,210,300,301,302,303,304,305,-1,-1,-1,-1,-1,-1,-1,-1,-1,-1,-1,
  12,13,14,15,35,36,37,38,105,106,107,108,109,110,111,112,113,114,211,212,213,214,215,216,260,261,262,306,307,308,309,310,311,
  15,38,115,116,117,118,119,120,121,122,123,124,217,218,219,220,221,222,263,312,313,314,315,316,317,-1,-1,-1,-1,-1,-1,-1,-1,
  125,126,127,128,129,130,131,132,133,134,223,224,225,226,227,228,318,319,320,321,322,323,-1,-1,-1,-1,-1,-1,-1,-1,-1,-1,-1,
  16,17,18,39,40,41,135,136,137,138,139,140,141,142,143,144,229,230,231,232,233,234,264,265,324,325,326,327,328,329,-1,-1,-1,
  18,41,145,146,147,148,149,150,151,152,153,154,235,236,237,238,239,240,266,330,331,332,333,334,335,-1,-1,-1,-1,-1,-1,-1,-1,
  19,20,21,42,43,44,155,156,157,158,159,160,161,162,163,164,241,242,243,244,245,246,267,268,336,337,338,339,340,341,-1,-1,-1,
  21,44,165,166,167,168,169,170,171,172,173,174,247,248,249,250,251,252,269,342,343,344,345,346,347,-1,-1,-1,-1,-1,-1,-1,-1
};

__device__ constexpr int ADJ[NN][3] = {
  {1,9,11},{0,2,0},{1,3,6},{2,4,0},{3,5,0},{4,0,0},{2,7,0},
  {6,8,0},{7,0,0},{0,10,0},{9,0,0},{0,12,0},{11,0,0}
};
__device__ constexpr int DEG[NN] = {3,2,3,2,2,1,2,2,1,2,1,2,1};
__device__ constexpr int JM0[NJ] = {1,1,1,2,2,2,3,2,2,2,6,0,0,9,0,0,11};
__device__ constexpr int JM1[NJ] = {2,2,2,3,3,3,4,6,6,6,7,9,9,10,11,11,12};

typedef float4 F4;
using s8v    = __attribute__((ext_vector_type(8)))  short;   // 8 bf16 (4 VGPR)
using f32x16 = __attribute__((ext_vector_type(16))) float;   // MFMA 32x32 C/D

__device__ __forceinline__ float elu1(float v) { return v > 0.0f ? v : expm1f(v); }

__device__ __forceinline__ unsigned short bf16r(float v) {   // round-to-nearest-even
  unsigned u = __float_as_uint(v);
  unsigned r = u + 0x7FFFu + ((u >> 16) & 1u);
  return (unsigned short)(r >> 16);
}
__device__ __forceinline__ float bf2f(unsigned short s) {
  return __uint_as_float(((unsigned)s) << 16);
}

// A-plane LDS addressing: row stride 256 shorts = 512 B. Each row = 32 units
// of 8 shorts (16 B); unit (2*oct + half) additively swizzled by row:
// phys_unit = (2*oct + half + row) & 31. Bijective per row, 16B alignment
// preserved, A-frag reads (rows base+l31, fixed oct) spread over all banks.
__device__ __forceinline__ int a_addr(int row, int col, int half) {
  const int u = (2 * (col >> 3) + half + row) & 31;
  return row * ASTRIDE + u * 8 + (col & 7);
}

// ---------------- pre-pass: split+swizzle Wmsg into frag-linear order -------
// (verbatim from the PASSING R6 kernel)
// ws u32 layout: [l(8)][ks(8)][kind(4: Thi,Tlo,Bhi,Blo)][nt(4)][lane(64)][j2(4)]
// value pair: k = ks*16 + (lane>>5)*8 + 2*j2 ; n = nt*32 + (lane&31)
// EXACT size: 8*8*4*4*64*4 = 262144 u32 = 1 MB -> grid 1024 x 256
__global__ void prep_wm(const float* __restrict__ Wm, unsigned* __restrict__ ws) {
  int i = blockIdx.x * 256 + threadIdx.x;      // 0 .. 262143
  int j2   = i & 3;
  int lane = (i >> 2) & 63;
  int nt   = (i >> 8) & 3;
  int kind = (i >> 10) & 3;
  int ks   = (i >> 12) & 7;
  int l    = i >> 15;                          // 0..7
  int k = ks * 16 + ((lane >> 5) * 8) + 2 * j2;
  int n = nt * 32 + (lane & 31);
  int rbase = (kind >= 2) ? 128 : 0;           // bottom half of Wmsg rows = agg part
  float v0 = Wm[((l * 256) + rbase + k) * HH + n];
  float v1 = Wm[((l * 256) + rbase + k + 1) * HH + n];
  unsigned short a, b;
  if ((kind & 1) == 0) { a = bf16r(v0); b = bf16r(v1); }
  else {
    a = bf16r(v0 - bf2f(bf16r(v0)));
    b = bf16r(v1 - bf2f(bf16r(v1)));
  }
  ws[i] = (unsigned)a | ((unsigned)b << 16);
}

// ---------------- main fused kernel (TB=16, 1024 threads) -------------------
__global__ __launch_bounds__(NTHR, 4)
void gnn_fused(const float* __restrict__ obs,
               const float* __restrict__ W1, const float* __restrict__ b1,
               const float* __restrict__ W2, const float* __restrict__ b2,
               const float* __restrict__ bm,
               const float* __restrict__ Wo, const float* __restrict__ bo,
               const float* __restrict__ wmsw,   // pre-swizzled Wmsg
               float* __restrict__ out)
{
  // A-planes: x state, 256 rows (elem*16+node), swizzled 16B units (hi|lo)
  __shared__ short As[256 * ASTRIDE];      // 131072 B ; aliased as fp32 h scratch
  __shared__ float Bb[2][4096];            // 2 x 16 KB ping-pong -> 163840 B total

  const int t    = threadIdx.x;
  const int wid  = t >> 6;        // wave 0..15
  const int mq   = wid >> 1;      // m-tile 0..7: rows mq*32 .. mq*32+31
  const int nh   = wid & 1;       // n-half
  const int lane = t & 63;
  const int l31  = lane & 31;
  const int lh   = lane >> 5;     // k-half within frag / row-group bit in C
  const bool h1  = (lh == 1);
  const int g    = t >> 5;        // 32-thread group 0..31 (VALU phases)
  const int og   = t & 31;
  const int o0   = og << 2;
  const int b0   = blockIdx.x * TB;

  const F4* wsrc4 = (const F4*)wmsw;
  float* hsc = (float*)As;        // h scratch (row stride HSTRIDE floats)
  F4* bufA = (F4*)Bb;             // 1024 F4 each
  F4* bufB = ((F4*)Bb) + 1024;
  float* xnb = (float*)Bb;        // xn gather scratch (16*13*36 = 7488 < 8192)

  // ---------- Phase 0: zero pad rows; gather xn ----------
  for (int i = t; i < 48 * HSTRIDE; i += NTHR) {   // rows elem*16+{13,14,15}
    int pr = i / HSTRIDE, off = i % HSTRIDE;
    int row = (pr / 3) * 16 + 13 + (pr % 3);
    ((int*)As)[row * HSTRIDE + off] = 0;
  }
  for (int i = t; i < TB * NN * DMAX; i += NTHR) {
    int d  = i % DMAX;
    int r  = i / DMAX;
    int nn = r % NN;
    int bb = r / NN;
    int fi = c_feat[nn * DMAX + d];
    float v = (fi >= 0) ? obs[(b0 + bb) * OBSD + fi] : 0.0f;
    xnb[(bb * NN + nn) * 36 + d] = v;
  }
  __syncthreads();

  // ---------- Phase 1 (VALU): h = elu(xn @ W1 + b1) -> hsc fp32 -------------
  {
    const int n  = g >> 1;         // 0..15, active < 13
    const int q0 = (g & 1) * 8;    // 8 elems per group
    if (n < NN) {
      float acc[8][4];
      const F4 bv = *(const F4*)(b1 + n * HH + o0);
      #pragma unroll
      for (int q = 0; q < 8; ++q) { acc[q][0]=bv.x; acc[q][1]=bv.y; acc[q][2]=bv.z; acc[q][3]=bv.w; }
      #pragma unroll 3
      for (int k = 0; k < DMAX; ++k) {
        const F4 w = *(const F4*)(W1 + (n * DMAX + k) * HH + o0);
        #pragma unroll
        for (int q = 0; q < 8; ++q) {
          const float xv = xnb[((q0 + q) * NN + n) * 36 + k];
          acc[q][0] += xv * w.x; acc[q][1] += xv * w.y;
          acc[q][2] += xv * w.z; acc[q][3] += xv * w.w;
        }
      }
      #pragma unroll
      for (int q = 0; q < 8; ++q) {
        F4 h;
        h.x = elu1(acc[q][0]); h.y = elu1(acc[q][1]);
        h.z = elu1(acc[q][2]); h.w = elu1(acc[q][3]);
        *(F4*)&hsc[((q0 + q) * 16 + n) * HSTRIDE + o0] = h;
      }
    }
  }
  __syncthreads();

  // ---------- Phase 2 (VALU): x = h @ W2 + b2 -> regs, then split-store ------
  float xacc[8][4];
  {
    const int n  = g >> 1;
    const int q0 = (g & 1) * 8;
    if (n < NN) {
      const F4 bv = *(const F4*)(b2 + n * HH + o0);
      #pragma unroll
      for (int q = 0; q < 8; ++q) {
        xacc[q][0]=bv.x; xacc[q][1]=bv.y; xacc[q][2]=bv.z; xacc[q][3]=bv.w;
      }
      #pragma unroll 2
      for (int k4 = 0; k4 < 32; ++k4) {
        const F4 w0 = *(const F4*)(W2 + (n * HH + k4*4 + 0) * HH + o0);
        const F4 w1 = *(const F4*)(W2 + (n * HH + k4*4 + 1) * HH + o0);
        const F4 w2 = *(const F4*)(W2 + (n * HH + k4*4 + 2) * HH + o0);
        const F4 w3 = *(const F4*)(W2 + (n * HH + k4*4 + 3) * HH + o0);
        #pragma unroll
        for (int q = 0; q < 8; ++q) {
          const F4 hv = *(const F4*)&hsc[((q0 + q) * 16 + n) * HSTRIDE + k4 * 4];
          xacc[q][0] += hv.x*w0.x + hv.y*w1.x + hv.z*w2.x + hv.w*w3.x;
          xacc[q][1] += hv.x*w0.y + hv.y*w1.y + hv.z*w2.y + hv.w*w3.y;
          xacc[q][2] += hv.x*w0.z + hv.y*w1.z + hv.z*w2.z + hv.w*w3.z;
          xacc[q][3] += hv.x*w0.w + hv.y*w1.w + hv.z*w2.w + hv.w*w3.w;
        }
      }
    }
  }
  __syncthreads();   // all h reads done; safe to overwrite As with x planes
  {
    const int n  = g >> 1;
    const int q0 = (g & 1) * 8;
    if (n < NN) {
      #pragma unroll
      for (int q = 0; q < 8; ++q) {
        #pragma unroll
        for (int cc = 0; cc < 4; ++cc) {
          float v = xacc[q][cc];
          unsigned short hs = bf16r(v);
          unsigned short ls = bf16r(v - bf2f(hs));
          const int row = (q0 + q) * 16 + n, col = o0 + cc;
          As[a_addr(row, col, 0)] = (short)hs;
          As[a_addr(row, col, 1)] = (short)ls;
        }
      }
    }
  }
  __syncthreads();

  // ---------- Phase 3: 8 MFMA layers (R6 3-term numerics) --------------------
  {
    // prologue: stage chunk 0 (1024 F4, one per thread)
    bufA[t] = wsrc4[t];
    __syncthreads();

    #pragma unroll 1
    for (int l = 0; l < NL; ++l) {
      f32x16 aT[2], aB[2];
      #pragma unroll
      for (int ni = 0; ni < 2; ++ni)
        #pragma unroll
        for (int r = 0; r < 16; ++r) { aT[ni][r] = 0.f; aB[ni][r] = 0.f; }

      #pragma unroll 2
      for (int ks = 0; ks < 8; ++ks) {
        const int gch = l * 8 + ks;          // global chunk index
        F4* cur = (gch & 1) ? bufB : bufA;
        F4* nxt = (gch & 1) ? bufA : bufB;

        F4 r0;
        const bool more = (gch < NL * 8 - 1);
        if (more) r0 = wsrc4[(size_t)(gch + 1) * 1024 + t];

        const short* bb = (const short*)cur;
        s8v ah, al;
        {
          const int row = mq * 32 + l31;
          const int p = 2 * ks + lh;         // oct index 0..15
          ah = *(const s8v*)(As + row * ASTRIDE + (((2 * p + row) & 31) * 8));
          al = *(const s8v*)(As + row * ASTRIDE + (((2 * p + 1 + row) & 31) * 8));
        }
        s8v bth[2], btl[2], bbh[2], bbl[2];
        #pragma unroll
        for (int ni = 0; ni < 2; ++ni) {
          const int ntab = nh * 2 + ni;
          bth[ni] = *(const s8v*)(bb + ((0 * 4 + ntab) * 64 + lane) * 8);
          btl[ni] = *(const s8v*)(bb + ((1 * 4 + ntab) * 64 + lane) * 8);
          bbh[ni] = *(const s8v*)(bb + ((2 * 4 + ntab) * 64 + lane) * 8);
          bbl[ni] = *(const s8v*)(bb + ((3 * 4 + ntab) * 64 + lane) * 8);
        }
        #pragma unroll
        for (int ni = 0; ni < 2; ++ni) {
          aT[ni] = __builtin_amdgcn_mfma_f32_32x32x16_bf16(ah, bth[ni], aT[ni], 0, 0, 0);
          aT[ni] = __builtin_amdgcn_mfma_f32_32x32x16_bf16(ah, btl[ni], aT[ni], 0, 0, 0);
          aT[ni] = __builtin_amdgcn_mfma_f32_32x32x16_bf16(al, bth[ni], aT[ni], 0, 0, 0);
          aB[ni] = __builtin_amdgcn_mfma_f32_32x32x16_bf16(ah, bbh[ni], aB[ni], 0, 0, 0);
          aB[ni] = __builtin_amdgcn_mfma_f32_32x32x16_bf16(ah, bbl[ni], aB[ni], 0, 0, 0);
          aB[ni] = __builtin_amdgcn_mfma_f32_32x32x16_bf16(al, bbh[ni], aB[ni], 0, 0, 0);
        }

        if (more) nxt[t] = r0;
        __syncthreads();   // publishes nxt; guards cur reuse and A-row overwrite
      }

      // epilogue: x_new = elu(Y_top + N*Y_bot + bias) ; split-store to As
      #pragma unroll
      for (int ni = 0; ni < 2; ++ni) {
        const int col  = (nh * 2 + ni) * 32 + l31;
        const float bias = bm[l * HH + col];
        float cb[16], sw[16];
        #pragma unroll
        for (int r = 0; r < 16; ++r) { cb[r] = aB[ni][r]; sw[r] = __shfl_xor(cb[r], 32); }

        #pragma unroll
        for (int r = 0; r < 16; ++r) {
          const int p  = (r & 3) + 8 * (r >> 2);
          const int n0 = p & 15;            // node for lane-half 0 (always < 13)
          const int n1 = n0 + 4;            // node for lane-half 1 (may be pad)
          const int es = p >> 4;
          #define SRCV(np)                                                \
            ({ const int rl = (es << 4) + (np);                           \
               const int hp = (rl >> 2) & 1;                              \
               const int pp = rl - 4 * hp;                                \
               const int rp = (pp & 3) + 4 * (pp >> 3);                   \
               (hp == 1) ? (h1 ? cb[rp] : sw[rp])                         \
                         : (h1 ? sw[rp] : cb[rp]); })
          float a0 = SRCV(ADJ[n0][0]);
          if (DEG[n0] > 1) a0 += SRCV(ADJ[n0][1]);
          if (DEG[n0] > 2) a0 += SRCV(ADJ[n0][2]);
          float a1 = 0.f;
          if (n1 < NN) {
            a1 = SRCV(ADJ[n1][0]);
            if (DEG[n1] > 1) a1 += SRCV(ADJ[n1][1]);
            if (DEG[n1] > 2) a1 += SRCV(ADJ[n1][2]);
          }
          #undef SRCV
          const float agg = h1 ? a1 : a0;
          const float tot = aT[ni][r] + agg + bias;
          float xv = elu1(tot);
          if (n1 >= NN) xv = h1 ? 0.f : xv;     // pad rows stay zero (stored)
          unsigned short hs = bf16r(xv);
          unsigned short ls = bf16r(xv - bf2f(hs));
          const int row = mq * 32 + p + 4 * lh;
          As[a_addr(row, col, 0)] = (short)hs;
          As[a_addr(row, col, 1)] = (short)ls;
        }
      }
      __syncthreads();
    }
  }

  // ---------- Phase 4: readout ----------------------------------------------
  if (g < TB) {
    const int elem = g;          // 0..15
    const int c = og * 4;        // 4 channels per thread
    float xv[NN][4];
    #pragma unroll
    for (int n = 0; n < NN; ++n) {
      const int row = elem * 16 + n;
      const ushort4 uh = *(const ushort4*)(As + a_addr(row, c, 0));
      const ushort4 ul = *(const ushort4*)(As + a_addr(row, c, 1));
      xv[n][0] = bf2f(uh.x) + bf2f(ul.x);
      xv[n][1] = bf2f(uh.y) + bf2f(ul.y);
      xv[n][2] = bf2f(uh.z) + bf2f(ul.z);
      xv[n][3] = bf2f(uh.w) + bf2f(ul.w);
    }
    #pragma unroll
    for (int j = 0; j < NJ; ++j) {
      const F4 wa = *(const F4*)(Wo + j * 256 + c);
      const F4 wb = *(const F4*)(Wo + j * 256 + 128 + c);
      const float* xa = xv[JM0[j]];
      const float* xb = xv[JM1[j]];
      float p = xa[0]*wa.x + xa[1]*wa.y + xa[2]*wa.z + xa[3]*wa.w
              + xb[0]*wb.x + xb[1]*wb.y + xb[2]*wb.z + xb[3]*wb.w;
      p += __shfl_xor(p, 16);
      p += __shfl_xor(p, 8);
      p += __shfl_xor(p, 4);
      p += __shfl_xor(p, 2);
      p += __shfl_xor(p, 1);
      if (og == 0) out[(b0 + elem) * NJ + j] = p + bo[j];
    }
  }
}

extern "C" void kernel_launch(void* const* d_in, const int* in_sizes, int n_in,
                              void* d_out, int out_size, void* d_ws, size_t ws_size,
                              hipStream_t stream) {
  const float* obs = (const float*)d_in[0];
  const float* W1  = (const float*)d_in[1];
  const float* b1  = (const float*)d_in[2];
  const float* W2  = (const float*)d_in[3];
  const float* b2  = (const float*)d_in[4];
  const float* Wm  = (const float*)d_in[5];
  const float* bm  = (const float*)d_in[6];
  const float* Wo  = (const float*)d_in[7];
  const float* bo  = (const float*)d_in[8];
  float* out = (float*)d_out;

  const int B = in_sizes[0] / OBSD;   // 16384
  const int nblk = B / TB;            // 1024

  // pre-pass: split Wmsg into bf16 hi/lo, frag-swizzled (exactly 1 MB in d_ws)
  prep_wm<<<1024, 256, 0, stream>>>(Wm, (unsigned*)d_ws);
  gnn_fused<<<nblk, NTHR, 0, stream>>>(obs, W1, b1, W2, b2, bm, Wo, bo,
                                       (const float*)d_ws, out);
}

// Round 10
// 793.610 us; speedup vs baseline: 1.3038x; 1.3038x over previous
//
#include <hip/hip_runtime.h>
#include <math.h>

#define NN   13
#define HH   128
#define NL   8
#define NJ   17
#define OBSD 348
#define DMAX 33
#define TB   8
#define NTHR 1024
#define ASTRIDE 264   // shorts per A row = 528 B (16B-aligned rows; R6-validated)
#define HSTRIDE 132   // same row viewed as fp32

// FEAT_IDX table (13 x 33), pad = -1
__constant__ int c_feat[NN * DMAX] = {
  0,1,2,3,4,22,23,24,25,26,27,45,46,47,48,49,50,51,52,53,54,175,176,177,178,179,180,270,271,272,273,274,275,
  5,6,28,29,55,56,57,58,59,60,61,62,63,64,181,182,183,184,185,186,276,277,278,279,280,281,-1,-1,-1,-1,-1,-1,-1,
  7,30,65,66,67,68,69,70,71,72,73,74,187,188,189,190,191,192,253,254,255,282,283,284,285,286,287,-1,-1,-1,-1,-1,-1,
  8,9,10,11,31,32,33,34,75,76,77,78,79,80,81,82,83,84,193,194,195,196,197,198,256,257,258,288,289,290,291,292,293,
  11,34,85,86,87,88,89,90,91,92,93,94,199,200,201,202,203,204,259,294,295,296,297,298,299,-1,-1,-1,-1,-1,-1,-1,-1,
  95,96,97,98,99,100,101,102,103,104,205,206,207,208,209,210,300,301,302,303,304,305,-1,-1,-1,-1,-1,-1,-1,-1,-1,-1,-1,
  12,13,14,15,35,36,37,38,105,106,107,108,109,110,111,112,113,114,211,212,213,214,215,216,260,261,262,306,307,308,309,310,311,
  15,38,115,116,117,118,119,120,121,122,123,124,217,218,219,220,221,222,263,312,313,314,315,316,317,-1,-1,-1,-1,-1,-1,-1,-1,
  125,126,127,128,129,130,131,132,133,134,223,224,225,226,227,228,318,319,320,321,322,323,-1,-1,-1,-1,-1,-1,-1,-1,-1,-1,-1,
  16,17,18,39,40,41,135,136,137,138,139,140,141,142,143,144,229,230,231,232,233,234,264,265,324,325,326,327,328,329,-1,-1,-1,
  18,41,145,146,147,148,149,150,151,152,153,154,235,236,237,238,239,240,266,330,331,332,333,334,335,-1,-1,-1,-1,-1,-1,-1,-1,
  19,20,21,42,43,44,155,156,157,158,159,160,161,162,163,164,241,242,243,244,245,246,267,268,336,337,338,339,340,341,-1,-1,-1,
  21,44,165,166,167,168,169,170,171,172,173,174,247,248,249,250,251,252,269,342,343,344,345,346,347,-1,-1,-1,-1,-1,-1,-1,-1
};

__device__ constexpr int ADJ[NN][3] = {
  {1,9,11},{0,2,0},{1,3,6},{2,4,0},{3,5,0},{4,0,0},{2,7,0},
  {6,8,0},{7,0,0},{0,10,0},{9,0,0},{0,12,0},{11,0,0}
};
__device__ constexpr int DEG[NN] = {3,2,3,2,2,1,2,2,1,2,1,2,1};
__device__ constexpr int JM0[NJ] = {1,1,1,2,2,2,3,2,2,2,6,0,0,9,0,0,11};
__device__ constexpr int JM1[NJ] = {2,2,2,3,3,3,4,6,6,6,7,9,9,10,11,11,12};

typedef float4 F4;
using s8v    = __attribute__((ext_vector_type(8)))  short;   // 8 bf16 (4 VGPR)
using f32x16 = __attribute__((ext_vector_type(16))) float;   // MFMA 32x32 C/D

__device__ __forceinline__ float elu1(float v) { return v > 0.0f ? v : expm1f(v); }

__device__ __forceinline__ unsigned short bf16r(float v) {   // round-to-nearest-even
  unsigned u = __float_as_uint(v);
  unsigned r = u + 0x7FFFu + ((u >> 16) & 1u);
  return (unsigned short)(r >> 16);
}
__device__ __forceinline__ float bf2f(unsigned short s) {
  return __uint_as_float(((unsigned)s) << 16);
}

// ---------------- pre-pass: split+swizzle Wmsg into frag-linear order -------
// (verbatim R6 — validated)
// ws u32 layout: [l(8)][ks(8)][kind(4: Thi,Tlo,Bhi,Blo)][nt(4)][lane(64)][j2(4)]
// value pair: k = ks*16 + (lane>>5)*8 + 2*j2 ; n = nt*32 + (lane&31)
// EXACT size: 8*8*4*4*64*4 = 262144 u32 = 1 MB -> grid 1024 x 256
__global__ void prep_wm(const float* __restrict__ Wm, unsigned* __restrict__ ws) {
  int i = blockIdx.x * 256 + threadIdx.x;      // 0 .. 262143
  int j2   = i & 3;
  int lane = (i >> 2) & 63;
  int nt   = (i >> 8) & 3;
  int kind = (i >> 10) & 3;
  int ks   = (i >> 12) & 7;
  int l    = i >> 15;                          // 0..7
  int k = ks * 16 + ((lane >> 5) * 8) + 2 * j2;
  int n = nt * 32 + (lane & 31);
  int rbase = (kind >= 2) ? 128 : 0;           // bottom half of Wmsg rows = agg part
  float v0 = Wm[((l * 256) + rbase + k) * HH + n];
  float v1 = Wm[((l * 256) + rbase + k + 1) * HH + n];
  unsigned short a, b;
  if ((kind & 1) == 0) { a = bf16r(v0); b = bf16r(v1); }
  else {
    a = bf16r(v0 - bf2f(bf16r(v0)));
    b = bf16r(v1 - bf2f(bf16r(v1)));
  }
  ws[i] = (unsigned)a | ((unsigned)b << 16);
}

// ---------------- main fused kernel (1024 thr, ONE block/CU, 1 tile/wave) ---
__global__ __launch_bounds__(NTHR, 4)
void gnn_fused(const float* __restrict__ obs,
               const float* __restrict__ W1, const float* __restrict__ b1,
               const float* __restrict__ W2, const float* __restrict__ b2,
               const float* __restrict__ bm,
               const float* __restrict__ Wo, const float* __restrict__ bo,
               const float* __restrict__ wmsw,   // pre-swizzled Wmsg
               float* __restrict__ out)
{
  // A-planes: x state, 128 rows (elem*16+node) x [oct(16B): hi 8 | lo 8] bf16
  __shared__ short As[128 * ASTRIDE];      // 67584 B ; aliased as fp32 h scratch
  __shared__ float Bb[2][4096];            // 2 x 16 KB ping-pong -> 100352 B (1 block/CU)

  const int t    = threadIdx.x;
  const int wid  = t >> 6;        // wave 0..15
  const int mq   = wid >> 2;      // m-tile 0..3: rows mq*32 .. mq*32+31
  const int nq   = wid & 3;       // n-quarter 0..3: cols nq*32 .. nq*32+31
  const int lane = t & 63;
  const int l31  = lane & 31;
  const int lh   = lane >> 5;     // k-half within frag / row-group bit in C
  const bool h1  = (lh == 1);
  const int g    = t >> 5;        // 32-thread group 0..31 (VALU phases)
  const int og   = t & 31;
  const int o0   = og << 2;
  const int b0   = blockIdx.x * TB;

  const F4* wsrc4 = (const F4*)wmsw;
  float* hsc = (float*)As;        // h scratch (row stride HSTRIDE floats)
  F4* bufA = (F4*)Bb;             // 1024 F4 each
  F4* bufB = ((F4*)Bb) + 1024;
  float* xnb = Bb[1];             // xn gather scratch (3744 floats < 4096)

  // ---------- Phase 0: zero pad rows; gather xn ----------
  for (int i = t; i < 24 * HSTRIDE; i += NTHR) {   // rows elem*16+{13,14,15}
    int pr = i / HSTRIDE, off = i % HSTRIDE;
    int row = (pr / 3) * 16 + 13 + (pr % 3);
    ((int*)As)[row * HSTRIDE + off] = 0;
  }
  for (int i = t; i < TB * NN * DMAX; i += NTHR) {
    int d  = i % DMAX;
    int r  = i / DMAX;
    int nn = r % NN;
    int bb = r / NN;
    int fi = c_feat[nn * DMAX + d];
    float v = (fi >= 0) ? obs[(b0 + bb) * OBSD + fi] : 0.0f;
    xnb[(bb * NN + nn) * 36 + d] = v;
  }
  __syncthreads();

  // ---------- Phase 1 (VALU): h = elu(xn @ W1 + b1) -> hsc fp32 -------------
  {
    const int n  = g >> 1;         // 0..15, active < 13
    const int q0 = (g & 1) * 4;    // 4 elems per group
    if (n < NN) {
      float acc[4][4];
      const F4 bv = *(const F4*)(b1 + n * HH + o0);
      #pragma unroll
      for (int q = 0; q < 4; ++q) { acc[q][0]=bv.x; acc[q][1]=bv.y; acc[q][2]=bv.z; acc[q][3]=bv.w; }
      #pragma unroll 3
      for (int k = 0; k < DMAX; ++k) {
        const F4 w = *(const F4*)(W1 + (n * DMAX + k) * HH + o0);
        #pragma unroll
        for (int q = 0; q < 4; ++q) {
          const float xv = xnb[((q0 + q) * NN + n) * 36 + k];
          acc[q][0] += xv * w.x; acc[q][1] += xv * w.y;
          acc[q][2] += xv * w.z; acc[q][3] += xv * w.w;
        }
      }
      #pragma unroll
      for (int q = 0; q < 4; ++q) {
        F4 h;
        h.x = elu1(acc[q][0]); h.y = elu1(acc[q][1]);
        h.z = elu1(acc[q][2]); h.w = elu1(acc[q][3]);
        *(F4*)&hsc[((q0 + q) * 16 + n) * HSTRIDE + o0] = h;
      }
    }
  }
  __syncthreads();

  // ---------- Phase 2 (VALU): x = h @ W2 + b2 -> regs, then split-store ------
  float xacc[4][4];
  {
    const int n  = g >> 1;
    const int q0 = (g & 1) * 4;
    if (n < NN) {
      const F4 bv = *(const F4*)(b2 + n * HH + o0);
      #pragma unroll
      for (int q = 0; q < 4; ++q) {
        xacc[q][0]=bv.x; xacc[q][1]=bv.y; xacc[q][2]=bv.z; xacc[q][3]=bv.w;
      }
      #pragma unroll 2
      for (int k4 = 0; k4 < 32; ++k4) {
        const F4 w0 = *(const F4*)(W2 + (n * HH + k4*4 + 0) * HH + o0);
        const F4 w1 = *(const F4*)(W2 + (n * HH + k4*4 + 1) * HH + o0);
        const F4 w2 = *(const F4*)(W2 + (n * HH + k4*4 + 2) * HH + o0);
        const F4 w3 = *(const F4*)(W2 + (n * HH + k4*4 + 3) * HH + o0);
        #pragma unroll
        for (int q = 0; q < 4; ++q) {
          const F4 hv = *(const F4*)&hsc[((q0 + q) * 16 + n) * HSTRIDE + k4 * 4];
          xacc[q][0] += hv.x*w0.x + hv.y*w1.x + hv.z*w2.x + hv.w*w3.x;
          xacc[q][1] += hv.x*w0.y + hv.y*w1.y + hv.z*w2.y + hv.w*w3.y;
          xacc[q][2] += hv.x*w0.z + hv.y*w1.z + hv.z*w2.z + hv.w*w3.z;
          xacc[q][3] += hv.x*w0.w + hv.y*w1.w + hv.z*w2.w + hv.w*w3.w;
        }
      }
    }
  }
  __syncthreads();   // all h reads done; safe to overwrite As with x planes
  {
    const int n  = g >> 1;
    const int q0 = (g & 1) * 4;
    if (n < NN) {
      #pragma unroll
      for (int q = 0; q < 4; ++q) {
        #pragma unroll
        for (int cc = 0; cc < 4; ++cc) {
          float v = xacc[q][cc];
          unsigned short hs = bf16r(v);
          unsigned short ls = bf16r(v - bf2f(hs));
          int col = o0 + cc;
          int ad  = ((q0 + q) * 16 + n) * ASTRIDE + ((col >> 3) << 4) + (col & 7);
          As[ad]     = (short)hs;
          As[ad + 8] = (short)ls;
        }
      }
    }
  }
  __syncthreads();

  // ---------- Phase 3: 8 MFMA layers (R6 protocol, 1 tile/wave) --------------
  {
    // prologue: stage chunk 0 (1024 F4, one per thread)
    bufA[t] = wsrc4[t];
    __syncthreads();

    #pragma unroll 1
    for (int l = 0; l < NL; ++l) {
      f32x16 aT, aB;
      #pragma unroll
      for (int r = 0; r < 16; ++r) { aT[r] = 0.f; aB[r] = 0.f; }

      #pragma unroll 2
      for (int ks = 0; ks < 8; ++ks) {
        const int gch = l * 8 + ks;          // global chunk index
        F4* cur = (gch & 1) ? bufB : bufA;
        F4* nxt = (gch & 1) ? bufA : bufB;

        F4 r0;
        const bool more = (gch < NL * 8 - 1);
        if (more) r0 = wsrc4[(size_t)(gch + 1) * 1024 + t];

        const short* bb = (const short*)cur;
        s8v ah, al;
        {
          const int row = mq * 32 + l31;
          const short* ap = As + row * ASTRIDE + (2 * ks + lh) * 16;
          ah = *(const s8v*)ap;
          al = *(const s8v*)(ap + 8);
        }
        const s8v bth = *(const s8v*)(bb + ((0 * 4 + nq) * 64 + lane) * 8);
        const s8v btl = *(const s8v*)(bb + ((1 * 4 + nq) * 64 + lane) * 8);
        const s8v bbh = *(const s8v*)(bb + ((2 * 4 + nq) * 64 + lane) * 8);
        const s8v bbl = *(const s8v*)(bb + ((3 * 4 + nq) * 64 + lane) * 8);

        aT = __builtin_amdgcn_mfma_f32_32x32x16_bf16(ah, bth, aT, 0, 0, 0);
        aT = __builtin_amdgcn_mfma_f32_32x32x16_bf16(ah, btl, aT, 0, 0, 0);
        aT = __builtin_amdgcn_mfma_f32_32x32x16_bf16(al, bth, aT, 0, 0, 0);
        aB = __builtin_amdgcn_mfma_f32_32x32x16_bf16(ah, bbh, aB, 0, 0, 0);
        aB = __builtin_amdgcn_mfma_f32_32x32x16_bf16(ah, bbl, aB, 0, 0, 0);
        aB = __builtin_amdgcn_mfma_f32_32x32x16_bf16(al, bbh, aB, 0, 0, 0);

        if (more) nxt[t] = r0;
        __syncthreads();   // publishes nxt; guards cur reuse and A-row overwrite
      }

      // epilogue: x_new = elu(Y_top + N*Y_bot + bias) ; split-store to As
      {
        const int col  = nq * 32 + l31;
        const float bias = bm[l * HH + col];
        float cb[16], sw[16];
        #pragma unroll
        for (int r = 0; r < 16; ++r) { cb[r] = aB[r]; sw[r] = __shfl_xor(cb[r], 32); }

        #pragma unroll
        for (int r = 0; r < 16; ++r) {
          const int p  = (r & 3) + 8 * (r >> 2);
          const int n0 = p & 15;            // node for lane-half 0 (always < 13)
          const int n1 = n0 + 4;            // node for lane-half 1 (may be pad)
          const int es = p >> 4;
          #define SRCV(np)                                                \
            ({ const int rl = (es << 4) + (np);                           \
               const int hp = (rl >> 2) & 1;                              \
               const int pp = rl - 4 * hp;                                \
               const int rp = (pp & 3) + 4 * (pp >> 3);                   \
               (hp == 1) ? (h1 ? cb[rp] : sw[rp])                         \
                         : (h1 ? sw[rp] : cb[rp]); })
          float a0 = SRCV(ADJ[n0][0]);
          if (DEG[n0] > 1) a0 += SRCV(ADJ[n0][1]);
          if (DEG[n0] > 2) a0 += SRCV(ADJ[n0][2]);
          float a1 = 0.f;
          if (n1 < NN) {
            a1 = SRCV(ADJ[n1][0]);
            if (DEG[n1] > 1) a1 += SRCV(ADJ[n1][1]);
            if (DEG[n1] > 2) a1 += SRCV(ADJ[n1][2]);
          }
          #undef SRCV
          const float agg = h1 ? a1 : a0;
          const float tot = aT[r] + agg + bias;
          float xv = elu1(tot);
          if (n1 >= NN) xv = h1 ? 0.f : xv;     // pad rows stay zero (stored)
          unsigned short hs = bf16r(xv);
          unsigned short ls = bf16r(xv - bf2f(hs));
          const int row = mq * 32 + p + 4 * lh;
          const int ad  = row * ASTRIDE + ((col >> 3) << 4) + (col & 7);
          As[ad]     = (short)hs;
          As[ad + 8] = (short)ls;
        }
      }
      __syncthreads();
    }
  }

  // ---------- Phase 4: readout ----------------------------------------------
  if (g < TB) {
    const int elem = g;          // 0..7
    const int c = og * 4;        // 4 channels per thread
    float xv[NN][4];
    #pragma unroll
    for (int n = 0; n < NN; ++n) {
      const int ad = (elem * 16 + n) * ASTRIDE + ((c >> 3) << 4) + (c & 7);
      const ushort4 uh = *(const ushort4*)(As + ad);
      const ushort4 ul = *(const ushort4*)(As + ad + 8);
      xv[n][0] = bf2f(uh.x) + bf2f(ul.x);
      xv[n][1] = bf2f(uh.y) + bf2f(ul.y);
      xv[n][2] = bf2f(uh.z) + bf2f(ul.z);
      xv[n][3] = bf2f(uh.w) + bf2f(ul.w);
    }
    #pragma unroll
    for (int j = 0; j < NJ; ++j) {
      const F4 wa = *(const F4*)(Wo + j * 256 + c);
      const F4 wb = *(const F4*)(Wo + j * 256 + 128 + c);
      const float* xa = xv[JM0[j]];
      const float* xb = xv[JM1[j]];
      float p = xa[0]*wa.x + xa[1]*wa.y + xa[2]*wa.z + xa[3]*wa.w
              + xb[0]*wb.x + xb[1]*wb.y + xb[2]*wb.z + xb[3]*wb.w;
      p += __shfl_xor(p, 16);
      p += __shfl_xor(p, 8);
      p += __shfl_xor(p, 4);
      p += __shfl_xor(p, 2);
      p += __shfl_xor(p, 1);
      if (og == 0) out[(b0 + elem) * NJ + j] = p + bo[j];
    }
  }
}

extern "C" void kernel_launch(void* const* d_in, const int* in_sizes, int n_in,
                              void* d_out, int out_size, void* d_ws, size_t ws_size,
                              hipStream_t stream) {
  const float* obs = (const float*)d_in[0];
  const float* W1  = (const float*)d_in[1];
  const float* b1  = (const float*)d_in[2];
  const float* W2  = (const float*)d_in[3];
  const float* b2  = (const float*)d_in[4];
  const float* Wm  = (const float*)d_in[5];
  const float* bm  = (const float*)d_in[6];
  const float* Wo  = (const float*)d_in[7];
  const float* bo  = (const float*)d_in[8];
  float* out = (float*)d_out;

  const int B = in_sizes[0] / OBSD;   // 16384
  const int nblk = B / TB;            // 2048

  // pre-pass: split Wmsg into bf16 hi/lo, frag-swizzled (exactly 1 MB in d_ws)
  prep_wm<<<1024, 256, 0, stream>>>(Wm, (unsigned*)d_ws);
  gnn_fused<<<nblk, NTHR, 0, stream>>>(obs, W1, b1, W2, b2, bm, Wo, bo,
                                       (const float*)d_ws, out);
}

// Round 11
// 733.112 us; speedup vs baseline: 1.4114x; 1.0825x over previous
//
#include <hip/hip_runtime.h>
#include <math.h>

#define NN   13
#define HH   128
#define NL   8
#define NJ   17
#define OBSD 348
#define DMAX 33
#define TB   8
#define NTHR 1024
#define ASTRIDE 256   // shorts per A row = 512 B; conflict-free via unit swizzle (R8-validated)
#define HSTRIDE 128   // same row viewed as fp32

// FEAT_IDX table (13 x 33), pad = -1
__constant__ int c_feat[NN * DMAX] = {
  0,1,2,3,4,22,23,24,25,26,27,45,46,47,48,49,50,51,52,53,54,175,176,177,178,179,180,270,271,272,273,274,275,
  5,6,28,29,55,56,57,58,59,60,61,62,63,64,181,182,183,184,185,186,276,277,278,279,280,281,-1,-1,-1,-1,-1,-1,-1,
  7,30,65,66,67,68,69,70,71,72,73,74,187,188,189,190,191,192,253,254,255,282,283,284,285,286,287,-1,-1,-1,-1,-1,-1,
  8,9,10,11,31,32,33,34,75,76,77,78,79,80,81,82,83,84,193,194,195,196,197,198,256,257,258,288,289,290,291,292,293,
  11,34,85,86,87,88,89,90,91,92,93,94,199,200,201,202,203,204,259,294,295,296,297,298,299,-1,-1,-1,-1,-1,-1,-1,-1,
  95,96,97,98,99,100,101,102,103,104,205,206,207,208,209,210,300,301,302,303,304,305,-1,-1,-1,-1,-1,-1,-1,-1,-1,-1,-1,
  12,13,14,15,35,36,37,38,105,106,107,108,109,110,111,112,113,114,211,212,213,214,215,216,260,261,262,306,307,308,309,310,311,
  15,38,115,116,117,118,119,120,121,122,123,124,217,218,219,220,221,222,263,312,313,314,315,316,317,-1,-1,-1,-1,-1,-1,-1,-1,
  125,126,127,128,129,130,131,132,133,134,223,224,225,226,227,228,318,319,320,321,322,323,-1,-1,-1,-1,-1,-1,-1,-1,-1,-1,-1,
  16,17,18,39,40,41,135,136,137,138,139,140,141,142,143,144,229,230,231,232,233,234,264,265,324,325,326,327,328,329,-1,-1,-1,
  18,41,145,146,147,148,149,150,151,152,153,154,235,236,237,238,239,240,266,330,331,332,333,334,335,-1,-1,-1,-1,-1,-1,-1,-1,
  19,20,21,42,43,44,155,156,157,158,159,160,161,162,163,164,241,242,243,244,245,246,267,268,336,337,338,339,340,341,-1,-1,-1,
  21,44,165,166,167,168,169,170,171,172,173,174,247,248,249,250,251,252,269,342,343,344,345,346,347,-1,-1,-1,-1,-1,-1,-1,-1
};

__device__ constexpr int ADJ[NN][3] = {
  {1,9,11},{0,2,0},{1,3,6},{2,4,0},{3,5,0},{4,0,0},{2,7,0},
  {6,8,0},{7,0,0},{0,10,0},{9,0,0},{0,12,0},{11,0,0}
};
__device__ constexpr int DEG[NN] = {3,2,3,2,2,1,2,2,1,2,1,2,1};
__device__ constexpr int JM0[NJ] = {1,1,1,2,2,2,3,2,2,2,6,0,0,9,0,0,11};
__device__ constexpr int JM1[NJ] = {2,2,2,3,3,3,4,6,6,6,7,9,9,10,11,11,12};

typedef float4 F4;
using s8v    = __attribute__((ext_vector_type(8)))  short;   // 8 bf16 (4 VGPR)
using f32x16 = __attribute__((ext_vector_type(16))) float;   // MFMA 32x32 C/D

// elu: for v<=0, expf(v)-1 has ~1e-7 ABS error (result in [-1,0]) — invisible
// vs the 0.0625 tolerance floor; saves ~6 VALU/inst vs expm1f.
__device__ __forceinline__ float elu1(float v) {
  return v > 0.0f ? v : (__expf(v) - 1.0f);
}

__device__ __forceinline__ unsigned short bf16r(float v) {   // round-to-nearest-even
  unsigned u = __float_as_uint(v);
  unsigned r = u + 0x7FFFu + ((u >> 16) & 1u);
  return (unsigned short)(r >> 16);
}
__device__ __forceinline__ float bf2f(unsigned short s) {
  return __uint_as_float(((unsigned)s) << 16);
}

// A-plane LDS addressing (validated end-to-end in R8's passing run):
// row stride 256 shorts = 512 B; row = 32 units of 8 shorts (16 B);
// phys_unit = (2*oct + half + row) & 31. Bijective per row, keeps 16B
// alignment, and makes A-frag reads (row = base + lane31, fixed oct) hit
// consecutive units -> conflict-free ds_read_b128.
__device__ __forceinline__ int a_addr(int row, int col, int half) {
  const int u = (2 * (col >> 3) + half + row) & 31;
  return row * ASTRIDE + u * 8 + (col & 7);
}

// ---------------- pre-pass: split+swizzle Wmsg into frag-linear order -------
// (verbatim R6/R10 — validated)
// ws u32 layout: [l(8)][ks(8)][kind(4: Thi,Tlo,Bhi,Blo)][nt(4)][lane(64)][j2(4)]
// value pair: k = ks*16 + (lane>>5)*8 + 2*j2 ; n = nt*32 + (lane&31)
// EXACT size: 8*8*4*4*64*4 = 262144 u32 = 1 MB -> grid 1024 x 256
__global__ void prep_wm(const float* __restrict__ Wm, unsigned* __restrict__ ws) {
  int i = blockIdx.x * 256 + threadIdx.x;      // 0 .. 262143
  int j2   = i & 3;
  int lane = (i >> 2) & 63;
  int nt   = (i >> 8) & 3;
  int kind = (i >> 10) & 3;
  int ks   = (i >> 12) & 7;
  int l    = i >> 15;                          // 0..7
  int k = ks * 16 + ((lane >> 5) * 8) + 2 * j2;
  int n = nt * 32 + (lane & 31);
  int rbase = (kind >= 2) ? 128 : 0;           // bottom half of Wmsg rows = agg part
  float v0 = Wm[((l * 256) + rbase + k) * HH + n];
  float v1 = Wm[((l * 256) + rbase + k + 1) * HH + n];
  unsigned short a, b;
  if ((kind & 1) == 0) { a = bf16r(v0); b = bf16r(v1); }
  else {
    a = bf16r(v0 - bf2f(bf16r(v0)));
    b = bf16r(v1 - bf2f(bf16r(v1)));
  }
  ws[i] = (unsigned)a | ((unsigned)b << 16);
}

// ---------------- main fused kernel (1024 thr, ONE block/CU, 1 tile/wave) ---
__global__ __launch_bounds__(NTHR, 4)
void gnn_fused(const float* __restrict__ obs,
               const float* __restrict__ W1, const float* __restrict__ b1,
               const float* __restrict__ W2, const float* __restrict__ b2,
               const float* __restrict__ bm,
               const float* __restrict__ Wo, const float* __restrict__ bo,
               const float* __restrict__ wmsw,   // pre-swizzled Wmsg
               float* __restrict__ out)
{
  // A-planes: x state, 128 rows (elem*16+node), swizzled 16B units (hi|lo)
  __shared__ short As[128 * ASTRIDE];      // 65536 B ; aliased as fp32 h scratch
  __shared__ float Bb[2][4096];            // 2 x 16 KB ping-pong -> 98304 B (1 block/CU)

  const int t    = threadIdx.x;
  const int wid  = t >> 6;        // wave 0..15
  const int mq   = wid >> 2;      // m-tile 0..3: rows mq*32 .. mq*32+31
  const int nq   = wid & 3;       // n-quarter 0..3: cols nq*32 .. nq*32+31
  const int lane = t & 63;
  const int l31  = lane & 31;
  const int lh   = lane >> 5;     // k-half within frag / row-group bit in C
  const bool h1  = (lh == 1);
  const int g    = t >> 5;        // 32-thread group 0..31 (VALU phases)
  const int og   = t & 31;
  const int o0   = og << 2;
  const int b0   = blockIdx.x * TB;

  const F4* wsrc4 = (const F4*)wmsw;
  float* hsc = (float*)As;        // h scratch (row stride HSTRIDE floats)
  F4* bufA = (F4*)Bb;             // 1024 F4 each
  F4* bufB = ((F4*)Bb) + 1024;
  float* xnb = Bb[1];             // xn gather scratch (3744 floats < 4096)

  // ---------- Phase 0: zero pad rows; gather xn ----------
  for (int i = t; i < 24 * HSTRIDE; i += NTHR) {   // rows elem*16+{13,14,15}
    int pr = i / HSTRIDE, off = i % HSTRIDE;
    int row = (pr / 3) * 16 + 13 + (pr % 3);
    ((int*)As)[row * HSTRIDE + off] = 0;           // whole row -> swizzle-safe
  }
  for (int i = t; i < TB * NN * DMAX; i += NTHR) {
    int d  = i % DMAX;
    int r  = i / DMAX;
    int nn = r % NN;
    int bb = r / NN;
    int fi = c_feat[nn * DMAX + d];
    float v = (fi >= 0) ? obs[(b0 + bb) * OBSD + fi] : 0.0f;
    xnb[(bb * NN + nn) * 36 + d] = v;
  }
  __syncthreads();

  // ---------- Phase 1 (VALU): h = elu(xn @ W1 + b1) -> hsc fp32 -------------
  {
    const int n  = g >> 1;         // 0..15, active < 13
    const int q0 = (g & 1) * 4;    // 4 elems per group
    if (n < NN) {
      float acc[4][4];
      const F4 bv = *(const F4*)(b1 + n * HH + o0);
      #pragma unroll
      for (int q = 0; q < 4; ++q) { acc[q][0]=bv.x; acc[q][1]=bv.y; acc[q][2]=bv.z; acc[q][3]=bv.w; }
      #pragma unroll 3
      for (int k = 0; k < DMAX; ++k) {
        const F4 w = *(const F4*)(W1 + (n * DMAX + k) * HH + o0);
        #pragma unroll
        for (int q = 0; q < 4; ++q) {
          const float xv = xnb[((q0 + q) * NN + n) * 36 + k];
          acc[q][0] += xv * w.x; acc[q][1] += xv * w.y;
          acc[q][2] += xv * w.z; acc[q][3] += xv * w.w;
        }
      }
      #pragma unroll
      for (int q = 0; q < 4; ++q) {
        F4 h;
        h.x = elu1(acc[q][0]); h.y = elu1(acc[q][1]);
        h.z = elu1(acc[q][2]); h.w = elu1(acc[q][3]);
        *(F4*)&hsc[((q0 + q) * 16 + n) * HSTRIDE + o0] = h;
      }
    }
  }
  __syncthreads();

  // ---------- Phase 2 (VALU): x = h @ W2 + b2 -> regs, then split-store ------
  float xacc[4][4];
  {
    const int n  = g >> 1;
    const int q0 = (g & 1) * 4;
    if (n < NN) {
      const F4 bv = *(const F4*)(b2 + n * HH + o0);
      #pragma unroll
      for (int q = 0; q < 4; ++q) {
        xacc[q][0]=bv.x; xacc[q][1]=bv.y; xacc[q][2]=bv.z; xacc[q][3]=bv.w;
      }
      #pragma unroll 2
      for (int k4 = 0; k4 < 32; ++k4) {
        const F4 w0 = *(const F4*)(W2 + (n * HH + k4*4 + 0) * HH + o0);
        const F4 w1 = *(const F4*)(W2 + (n * HH + k4*4 + 1) * HH + o0);
        const F4 w2 = *(const F4*)(W2 + (n * HH + k4*4 + 2) * HH + o0);
        const F4 w3 = *(const F4*)(W2 + (n * HH + k4*4 + 3) * HH + o0);
        #pragma unroll
        for (int q = 0; q < 4; ++q) {
          const F4 hv = *(const F4*)&hsc[((q0 + q) * 16 + n) * HSTRIDE + k4 * 4];
          xacc[q][0] += hv.x*w0.x + hv.y*w1.x + hv.z*w2.x + hv.w*w3.x;
          xacc[q][1] += hv.x*w0.y + hv.y*w1.y + hv.z*w2.y + hv.w*w3.y;
          xacc[q][2] += hv.x*w0.z + hv.y*w1.z + hv.z*w2.z + hv.w*w3.z;
          xacc[q][3] += hv.x*w0.w + hv.y*w1.w + hv.z*w2.w + hv.w*w3.w;
        }
      }
    }
  }
  __syncthreads();   // all h reads done; safe to overwrite As with x planes
  {
    const int n  = g >> 1;
    const int q0 = (g & 1) * 4;
    if (n < NN) {
      #pragma unroll
      for (int q = 0; q < 4; ++q) {
        #pragma unroll
        for (int cc = 0; cc < 4; ++cc) {
          float v = xacc[q][cc];
          unsigned short hs = bf16r(v);
          unsigned short ls = bf16r(v - bf2f(hs));
          const int row = (q0 + q) * 16 + n, col = o0 + cc;
          As[a_addr(row, col, 0)] = (short)hs;
          As[a_addr(row, col, 1)] = (short)ls;
        }
      }
    }
  }
  __syncthreads();

  // ---------- Phase 3: 8 MFMA layers (R10 protocol, swizzled A) --------------
  {
    // prologue: stage chunk 0 (1024 F4, one per thread)
    bufA[t] = wsrc4[t];
    __syncthreads();

    #pragma unroll 1
    for (int l = 0; l < NL; ++l) {
      f32x16 aT, aB;
      #pragma unroll
      for (int r = 0; r < 16; ++r) { aT[r] = 0.f; aB[r] = 0.f; }

      #pragma unroll 2
      for (int ks = 0; ks < 8; ++ks) {
        const int gch = l * 8 + ks;          // global chunk index
        F4* cur = (gch & 1) ? bufB : bufA;
        F4* nxt = (gch & 1) ? bufA : bufB;

        F4 r0;
        const bool more = (gch < NL * 8 - 1);
        if (more) r0 = wsrc4[(size_t)(gch + 1) * 1024 + t];

        const short* bb = (const short*)cur;
        s8v ah, al;
        {
          const int row = mq * 32 + l31;
          const int p = 2 * ks + lh;         // oct index 0..15
          ah = *(const s8v*)(As + row * ASTRIDE + (((2 * p + row) & 31) * 8));
          al = *(const s8v*)(As + row * ASTRIDE + (((2 * p + 1 + row) & 31) * 8));
        }
        const s8v bth = *(const s8v*)(bb + ((0 * 4 + nq) * 64 + lane) * 8);
        const s8v btl = *(const s8v*)(bb + ((1 * 4 + nq) * 64 + lane) * 8);
        const s8v bbh = *(const s8v*)(bb + ((2 * 4 + nq) * 64 + lane) * 8);
        const s8v bbl = *(const s8v*)(bb + ((3 * 4 + nq) * 64 + lane) * 8);

        aT = __builtin_amdgcn_mfma_f32_32x32x16_bf16(ah, bth, aT, 0, 0, 0);
        aT = __builtin_amdgcn_mfma_f32_32x32x16_bf16(ah, btl, aT, 0, 0, 0);
        aT = __builtin_amdgcn_mfma_f32_32x32x16_bf16(al, bth, aT, 0, 0, 0);
        aB = __builtin_amdgcn_mfma_f32_32x32x16_bf16(ah, bbh, aB, 0, 0, 0);
        aB = __builtin_amdgcn_mfma_f32_32x32x16_bf16(ah, bbl, aB, 0, 0, 0);
        aB = __builtin_amdgcn_mfma_f32_32x32x16_bf16(al, bbh, aB, 0, 0, 0);

        if (more) nxt[t] = r0;
        __syncthreads();   // publishes nxt; guards cur reuse and A-row overwrite
      }

      // epilogue: x_new = elu(Y_top + N*Y_bot + bias) ; split-store to As
      {
        const int col  = nq * 32 + l31;
        const float bias = bm[l * HH + col];
        float cb[16], sw[16];
        #pragma unroll
        for (int r = 0; r < 16; ++r) { cb[r] = aB[r]; sw[r] = __shfl_xor(cb[r], 32); }

        #pragma unroll
        for (int r = 0; r < 16; ++r) {
          const int p  = (r & 3) + 8 * (r >> 2);
          const int n0 = p & 15;            // node for lane-half 0 (always < 13)
          const int n1 = n0 + 4;            // node for lane-half 1 (may be pad)
          const int es = p >> 4;
          #define SRCV(np)                                                \
            ({ const int rl = (es << 4) + (np);                           \
               const int hp = (rl >> 2) & 1;                              \
               const int pp = rl - 4 * hp;                                \
               const int rp = (pp & 3) + 4 * (pp >> 3);                   \
               (hp == 1) ? (h1 ? cb[rp] : sw[rp])                         \
                         : (h1 ? sw[rp] : cb[rp]); })
          float a0 = SRCV(ADJ[n0][0]);
          if (DEG[n0] > 1) a0 += SRCV(ADJ[n0][1]);
          if (DEG[n0] > 2) a0 += SRCV(ADJ[n0][2]);
          float a1 = 0.f;
          if (n1 < NN) {
            a1 = SRCV(ADJ[n1][0]);
            if (DEG[n1] > 1) a1 += SRCV(ADJ[n1][1]);
            if (DEG[n1] > 2) a1 += SRCV(ADJ[n1][2]);
          }
          #undef SRCV
          const float agg = h1 ? a1 : a0;
          const float tot = aT[r] + agg + bias;
          float xv = elu1(tot);
          if (n1 >= NN) xv = h1 ? 0.f : xv;     // pad rows stay zero (stored)
          unsigned short hs = bf16r(xv);
          unsigned short ls = bf16r(xv - bf2f(hs));
          const int row = mq * 32 + p + 4 * lh;
          As[a_addr(row, col, 0)] = (short)hs;
          As[a_addr(row, col, 1)] = (short)ls;
        }
      }
      __syncthreads();
    }
  }

  // ---------- Phase 4: readout ----------------------------------------------
  if (g < TB) {
    const int elem = g;          // 0..7
    const int c = og * 4;        // 4 channels per thread
    float xv[NN][4];
    #pragma unroll
    for (int n = 0; n < NN; ++n) {
      const int row = elem * 16 + n;
      const ushort4 uh = *(const ushort4*)(As + a_addr(row, c, 0));
      const ushort4 ul = *(const ushort4*)(As + a_addr(row, c, 1));
      xv[n][0] = bf2f(uh.x) + bf2f(ul.x);
      xv[n][1] = bf2f(uh.y) + bf2f(ul.y);
      xv[n][2] = bf2f(uh.z) + bf2f(ul.z);
      xv[n][3] = bf2f(uh.w) + bf2f(ul.w);
    }
    #pragma unroll
    for (int j = 0; j < NJ; ++j) {
      const F4 wa = *(const F4*)(Wo + j * 256 + c);
      const F4 wb = *(const F4*)(Wo + j * 256 + 128 + c);
      const float* xa = xv[JM0[j]];
      const float* xb = xv[JM1[j]];
      float p = xa[0]*wa.x + xa[1]*wa.y + xa[2]*wa.z + xa[3]*wa.w
              + xb[0]*wb.x + xb[1]*wb.y + xb[2]*wb.z + xb[3]*wb.w;
      p += __shfl_xor(p, 16);
      p += __shfl_xor(p, 8);
      p += __shfl_xor(p, 4);
      p += __shfl_xor(p, 2);
      p += __shfl_xor(p, 1);
      if (og == 0) out[(b0 + elem) * NJ + j] = p + bo[j];
    }
  }
}

extern "C" void kernel_launch(void* const* d_in, const int* in_sizes, int n_in,
                              void* d_out, int out_size, void* d_ws, size_t ws_size,
                              hipStream_t stream) {
  const float* obs = (const float*)d_in[0];
  const float* W1  = (const float*)d_in[1];
  const float* b1  = (const float*)d_in[2];
  const float* W2  = (const float*)d_in[3];
  const float* b2  = (const float*)d_in[4];
  const float* Wm  = (const float*)d_in[5];
  const float* bm  = (const float*)d_in[6];
  const float* Wo  = (const float*)d_in[7];
  const float* bo  = (const float*)d_in[8];
  float* out = (float*)d_out;

  const int B = in_sizes[0] / OBSD;   // 16384
  const int nblk = B / TB;            // 2048

  // pre-pass: split Wmsg into bf16 hi/lo, frag-swizzled (exactly 1 MB in d_ws)
  prep_wm<<<1024, 256, 0, stream>>>(Wm, (unsigned*)d_ws);
  gnn_fused<<<nblk, NTHR, 0, stream>>>(obs, W1, b1, W2, b2, bm, Wo, bo,
                                       (const float*)d_ws, out);
}

// Round 13
// 725.608 us; speedup vs baseline: 1.4260x; 1.0103x over previous
//
#include <hip/hip_runtime.h>
#include <math.h>

#define NN   13
#define HH   128
#define NL   8
#define NJ   17
#define OBSD 348
#define DMAX 33
#define TB   8
#define NTHR 1024
#define ASTRIDE 256   // shorts per A row = 512 B; unit-swizzled (R8/R11-validated)
#define HSTRIDE 128   // same row viewed as fp32

// FEAT_IDX table (13 x 33), pad = -1
__constant__ int c_feat[NN * DMAX] = {
  0,1,2,3,4,22,23,24,25,26,27,45,46,47,48,49,50,51,52,53,54,175,176,177,178,179,180,270,271,272,273,274,275,
  5,6,28,29,55,56,57,58,59,60,61,62,63,64,181,182,183,184,185,186,276,277,278,279,280,281,-1,-1,-1,-1,-1,-1,-1,
  7,30,65,66,67,68,69,70,71,72,73,74,187,188,189,190,191,192,253,254,255,282,283,284,285,286,287,-1,-1,-1,-1,-1,-1,
  8,9,10,11,31,32,33,34,75,76,77,78,79,80,81,82,83,84,193,194,195,196,197,198,256,257,258,288,289,290,291,292,293,
  11,34,85,86,87,88,89,90,91,92,93,94,199,200,201,202,203,204,259,294,295,296,297,298,299,-1,-1,-1,-1,-1,-1,-1,-1,
  95,96,97,98,99,100,101,102,103,104,205,206,207,208,209,210,300,301,302,303,304,305,-1,-1,-1,-1,-1,-1,-1,-1,-1,-1,-1,
  12,13,14,15,35,36,37,38,105,106,107,108,109,110,111,112,113,114,211,212,213,214,215,216,260,261,262,306,307,308,309,310,311,
  15,38,115,116,117,118,119,120,121,122,123,124,217,218,219,220,221,222,263,312,313,314,315,316,317,-1,-1,-1,-1,-1,-1,-1,-1,
  125,126,127,128,129,130,131,132,133,134,223,224,225,226,227,228,318,319,320,321,322,323,-1,-1,-1,-1,-1,-1,-1,-1,-1,-1,-1,
  16,17,18,39,40,41,135,136,137,138,139,140,141,142,143,144,229,230,231,232,233,234,264,265,324,325,326,327,328,329,-1,-1,-1,
  18,41,145,146,147,148,149,150,151,152,153,154,235,236,237,238,239,240,266,330,331,332,333,334,335,-1,-1,-1,-1,-1,-1,-1,-1,
  19,20,21,42,43,44,155,156,157,158,159,160,161,162,163,164,241,242,243,244,245,246,267,268,336,337,338,339,340,341,-1,-1,-1,
  21,44,165,166,167,168,169,170,171,172,173,174,247,248,249,250,251,252,269,342,343,344,345,346,347,-1,-1,-1,-1,-1,-1,-1,-1
};

__device__ constexpr int ADJ[NN][3] = {
  {1,9,11},{0,2,0},{1,3,6},{2,4,0},{3,5,0},{4,0,0},{2,7,0},
  {6,8,0},{7,0,0},{0,10,0},{9,0,0},{0,12,0},{11,0,0}
};
__device__ constexpr int DEG[NN] = {3,2,3,2,2,1,2,2,1,2,1,2,1};
__device__ constexpr int JM0[NJ] = {1,1,1,2,2,2,3,2,2,2,6,0,0,9,0,0,11};
__device__ constexpr int JM1[NJ] = {2,2,2,3,3,3,4,6,6,6,7,9,9,10,11,11,12};

typedef float4 F4;
using s8v    = __attribute__((ext_vector_type(8)))  short;   // 8 bf16 (4 VGPR)
using f32x16 = __attribute__((ext_vector_type(16))) float;   // MFMA 32x32 C/D

// elu: for v<=0, __expf(v)-1 ~1e-7 abs err — invisible vs 0.0625 floor (R11-validated)
__device__ __forceinline__ float elu1(float v) {
  return v > 0.0f ? v : (__expf(v) - 1.0f);
}

__device__ __forceinline__ unsigned short bf16r(float v) {   // round-to-nearest-even
  unsigned u = __float_as_uint(v);
  unsigned r = u + 0x7FFFu + ((u >> 16) & 1u);
  return (unsigned short)(r >> 16);
}
__device__ __forceinline__ float bf2f(unsigned short s) {
  return __uint_as_float(((unsigned)s) << 16);
}

// A-plane LDS addressing (R8/R11-validated): phys_unit = (2*oct+half+row)&31
__device__ __forceinline__ int a_addr(int row, int col, int half) {
  const int u = (2 * (col >> 3) + half + row) & 31;
  return row * ASTRIDE + u * 8 + (col & 7);
}

// ---------------- pre-pass: split+swizzle Wmsg into frag-linear order -------
// (verbatim R6/R10/R11 — validated)
__global__ void prep_wm(const float* __restrict__ Wm, unsigned* __restrict__ ws) {
  int i = blockIdx.x * 256 + threadIdx.x;      // 0 .. 262143
  int j2   = i & 3;
  int lane = (i >> 2) & 63;
  int nt   = (i >> 8) & 3;
  int kind = (i >> 10) & 3;
  int ks   = (i >> 12) & 7;
  int l    = i >> 15;                          // 0..7
  int k = ks * 16 + ((lane >> 5) * 8) + 2 * j2;
  int n = nt * 32 + (lane & 31);
  int rbase = (kind >= 2) ? 128 : 0;           // bottom half of Wmsg rows = agg part
  float v0 = Wm[((l * 256) + rbase + k) * HH + n];
  float v1 = Wm[((l * 256) + rbase + k + 1) * HH + n];
  unsigned short a, b;
  if ((kind & 1) == 0) { a = bf16r(v0); b = bf16r(v1); }
  else {
    a = bf16r(v0 - bf2f(bf16r(v0)));
    b = bf16r(v1 - bf2f(bf16r(v1)));
  }
  ws[i] = (unsigned)a | ((unsigned)b << 16);
}

// ---------------- main fused kernel (1024 thr, ONE block/CU, 1 tile/wave) ---
__global__ __launch_bounds__(NTHR, 4)
void gnn_fused(const float* __restrict__ obs,
               const float* __restrict__ W1, const float* __restrict__ b1,
               const float* __restrict__ W2, const float* __restrict__ b2,
               const float* __restrict__ bm,
               const float* __restrict__ Wo, const float* __restrict__ bo,
               const float* __restrict__ wmsw,   // pre-swizzled Wmsg
               float* __restrict__ out)
{
  // A-planes: x state, 128 rows (elem*16+node), swizzled 16B units (hi|lo)
  __shared__ short As[128 * ASTRIDE];      // 65536 B ; aliased as fp32 h scratch
  __shared__ float Bb[2][8192];            // 2 x 32 KB (ks-PAIR) ping-pong -> 131072 B

  const int t    = threadIdx.x;
  const int wid  = t >> 6;        // wave 0..15
  const int mq   = wid >> 2;      // m-tile 0..3: rows mq*32 .. mq*32+31
  const int nq   = wid & 3;       // n-quarter 0..3: cols nq*32 .. nq*32+31
  const int lane = t & 63;
  const int l31  = lane & 31;
  const int lh   = lane >> 5;     // k-half within frag / row-group bit in C
  const bool h1  = (lh == 1);
  const int g    = t >> 5;        // 32-thread group 0..31 (VALU phases)
  const int og   = t & 31;
  const int o0   = og << 2;
  const int b0   = blockIdx.x * TB;

  const F4* wsrc4 = (const F4*)wmsw;
  float* hsc = (float*)As;        // h scratch (row stride HSTRIDE floats)
  F4* bufA = (F4*)Bb;             // 2048 F4 each
  F4* bufB = ((F4*)Bb) + 2048;
  float* xnb = Bb[1];             // xn gather scratch (3744 floats < 8192)

  // ---------- Phase 0: zero pad rows; gather xn ----------
  for (int i = t; i < 24 * HSTRIDE; i += NTHR) {   // rows elem*16+{13,14,15}
    int pr = i / HSTRIDE, off = i % HSTRIDE;
    int row = (pr / 3) * 16 + 13 + (pr % 3);
    ((int*)As)[row * HSTRIDE + off] = 0;           // whole row -> swizzle-safe
  }
  for (int i = t; i < TB * NN * DMAX; i += NTHR) {
    int d  = i % DMAX;
    int r  = i / DMAX;
    int nn = r % NN;
    int bb = r / NN;
    int fi = c_feat[nn * DMAX + d];
    float v = (fi >= 0) ? obs[(b0 + bb) * OBSD + fi] : 0.0f;
    xnb[(bb * NN + nn) * 36 + d] = v;
  }
  __syncthreads();

  // ---------- Phase 1 (VALU): h = elu(xn @ W1 + b1) -> hsc fp32 -------------
  {
    const int n  = g >> 1;         // 0..15, active < 13
    const int q0 = (g & 1) * 4;    // 4 elems per group
    if (n < NN) {
      float acc[4][4];
      const F4 bv = *(const F4*)(b1 + n * HH + o0);
      #pragma unroll
      for (int q = 0; q < 4; ++q) { acc[q][0]=bv.x; acc[q][1]=bv.y; acc[q][2]=bv.z; acc[q][3]=bv.w; }
      #pragma unroll 3
      for (int k = 0; k < DMAX; ++k) {
        const F4 w = *(const F4*)(W1 + (n * DMAX + k) * HH + o0);
        #pragma unroll
        for (int q = 0; q < 4; ++q) {
          const float xv = xnb[((q0 + q) * NN + n) * 36 + k];
          acc[q][0] += xv * w.x; acc[q][1] += xv * w.y;
          acc[q][2] += xv * w.z; acc[q][3] += xv * w.w;
        }
      }
      #pragma unroll
      for (int q = 0; q < 4; ++q) {
        F4 h;
        h.x = elu1(acc[q][0]); h.y = elu1(acc[q][1]);
        h.z = elu1(acc[q][2]); h.w = elu1(acc[q][3]);
        *(F4*)&hsc[((q0 + q) * 16 + n) * HSTRIDE + o0] = h;
      }
    }
  }
  __syncthreads();

  // ---------- Phase 2 (VALU): x = h @ W2 + b2 -> regs, then split-store ------
  float xacc[4][4];
  {
    const int n  = g >> 1;
    const int q0 = (g & 1) * 4;
    if (n < NN) {
      const F4 bv = *(const F4*)(b2 + n * HH + o0);
      #pragma unroll
      for (int q = 0; q < 4; ++q) {
        xacc[q][0]=bv.x; xacc[q][1]=bv.y; xacc[q][2]=bv.z; xacc[q][3]=bv.w;
      }
      #pragma unroll 2
      for (int k4 = 0; k4 < 32; ++k4) {
        const F4 w0 = *(const F4*)(W2 + (n * HH + k4*4 + 0) * HH + o0);
        const F4 w1 = *(const F4*)(W2 + (n * HH + k4*4 + 1) * HH + o0);
        const F4 w2 = *(const F4*)(W2 + (n * HH + k4*4 + 2) * HH + o0);
        const F4 w3 = *(const F4*)(W2 + (n * HH + k4*4 + 3) * HH + o0);
        #pragma unroll
        for (int q = 0; q < 4; ++q) {
          const F4 hv = *(const F4*)&hsc[((q0 + q) * 16 + n) * HSTRIDE + k4 * 4];
          xacc[q][0] += hv.x*w0.x + hv.y*w1.x + hv.z*w2.x + hv.w*w3.x;
          xacc[q][1] += hv.x*w0.y + hv.y*w1.y + hv.z*w2.y + hv.w*w3.y;
          xacc[q][2] += hv.x*w0.z + hv.y*w1.z + hv.z*w2.z + hv.w*w3.z;
          xacc[q][3] += hv.x*w0.w + hv.y*w1.w + hv.z*w2.w + hv.w*w3.w;
        }
      }
    }
  }
  __syncthreads();   // all h reads done; safe to overwrite As with x planes
  {
    const int n  = g >> 1;
    const int q0 = (g & 1) * 4;
    if (n < NN) {
      #pragma unroll
      for (int q = 0; q < 4; ++q) {
        #pragma unroll
        for (int cc = 0; cc < 4; ++cc) {
          float v = xacc[q][cc];
          unsigned short hs = bf16r(v);
          unsigned short ls = bf16r(v - bf2f(hs));
          const int row = (q0 + q) * 16 + n, col = o0 + cc;
          As[a_addr(row, col, 0)] = (short)hs;
          As[a_addr(row, col, 1)] = (short)ls;
        }
      }
    }
  }
  __syncthreads();

  // ---------- Phase 3: 8 MFMA layers (ks-PAIR chunks: 4+1 barriers/layer) ----
  {
    // prologue: stage pair 0 (2048 F4, two per thread)
    bufA[t] = wsrc4[t]; bufA[t + 1024] = wsrc4[t + 1024];
    __syncthreads();

    #pragma unroll 1
    for (int l = 0; l < NL; ++l) {
      f32x16 aT, aB;
      #pragma unroll
      for (int r = 0; r < 16; ++r) { aT[r] = 0.f; aB[r] = 0.f; }

      #pragma unroll 1
      for (int kp = 0; kp < 4; ++kp) {
        const int gpc = l * 4 + kp;          // global pair index 0..31
        F4* cur = (gpc & 1) ? bufB : bufA;
        F4* nxt = (gpc & 1) ? bufA : bufB;

        F4 r0, r1;
        const bool more = (gpc < NL * 4 - 1);
        if (more) {
          const F4* s = wsrc4 + (size_t)(gpc + 1) * 2048;
          r0 = s[t]; r1 = s[t + 1024];
        }

        #pragma unroll
        for (int kk = 0; kk < 2; ++kk) {
          const int ks = kp * 2 + kk;
          // 16 KB sub-chunk = 8192 SHORTS (R12 bug was kk*16384 -> OOB/NaN)
          const short* bb = ((const short*)cur) + kk * 8192;

          s8v ah, al;
          {
            const int row = mq * 32 + l31;
            const int p = 2 * ks + lh;         // oct index 0..15
            ah = *(const s8v*)(As + row * ASTRIDE + (((2 * p + row) & 31) * 8));
            al = *(const s8v*)(As + row * ASTRIDE + (((2 * p + 1 + row) & 31) * 8));
          }
          const s8v bth = *(const s8v*)(bb + ((0 * 4 + nq) * 64 + lane) * 8);
          const s8v btl = *(const s8v*)(bb + ((1 * 4 + nq) * 64 + lane) * 8);
          const s8v bbh = *(const s8v*)(bb + ((2 * 4 + nq) * 64 + lane) * 8);
          const s8v bbl = *(const s8v*)(bb + ((3 * 4 + nq) * 64 + lane) * 8);

          aT = __builtin_amdgcn_mfma_f32_32x32x16_bf16(ah, bth, aT, 0, 0, 0);
          aT = __builtin_amdgcn_mfma_f32_32x32x16_bf16(ah, btl, aT, 0, 0, 0);
          aT = __builtin_amdgcn_mfma_f32_32x32x16_bf16(al, bth, aT, 0, 0, 0);
          aB = __builtin_amdgcn_mfma_f32_32x32x16_bf16(ah, bbh, aB, 0, 0, 0);
          aB = __builtin_amdgcn_mfma_f32_32x32x16_bf16(ah, bbl, aB, 0, 0, 0);
          aB = __builtin_amdgcn_mfma_f32_32x32x16_bf16(al, bbh, aB, 0, 0, 0);
        }

        if (more) { nxt[t] = r0; nxt[t + 1024] = r1; }
        __syncthreads();   // publishes nxt; guards cur reuse and A-row overwrite
      }

      // epilogue: x_new = elu(Y_top + N*Y_bot + bias) ; split-store to As
      {
        const int col  = nq * 32 + l31;
        const float bias = bm[l * HH + col];
        float cb[16], sw[16];
        #pragma unroll
        for (int r = 0; r < 16; ++r) { cb[r] = aB[r]; sw[r] = __shfl_xor(cb[r], 32); }

        #pragma unroll
        for (int r = 0; r < 16; ++r) {
          const int p  = (r & 3) + 8 * (r >> 2);
          const int n0 = p & 15;            // node for lane-half 0 (always < 13)
          const int n1 = n0 + 4;            // node for lane-half 1 (may be pad)
          const int es = p >> 4;
          #define SRCV(np)                                                \
            ({ const int rl = (es << 4) + (np);                           \
               const int hp = (rl >> 2) & 1;                              \
               const int pp = rl - 4 * hp;                                \
               const int rp = (pp & 3) + 4 * (pp >> 3);                   \
               (hp == 1) ? (h1 ? cb[rp] : sw[rp])                         \
                         : (h1 ? sw[rp] : cb[rp]); })
          float a0 = SRCV(ADJ[n0][0]);
          if (DEG[n0] > 1) a0 += SRCV(ADJ[n0][1]);
          if (DEG[n0] > 2) a0 += SRCV(ADJ[n0][2]);
          float a1 = 0.f;
          if (n1 < NN) {
            a1 = SRCV(ADJ[n1][0]);
            if (DEG[n1] > 1) a1 += SRCV(ADJ[n1][1]);
            if (DEG[n1] > 2) a1 += SRCV(ADJ[n1][2]);
          }
          #undef SRCV
          const float agg = h1 ? a1 : a0;
          const float tot = aT[r] + agg + bias;
          float xv = elu1(tot);
          if (n1 >= NN) xv = h1 ? 0.f : xv;     // pad rows stay zero (stored)
          unsigned short hs = bf16r(xv);
          unsigned short ls = bf16r(xv - bf2f(hs));
          const int row = mq * 32 + p + 4 * lh;
          As[a_addr(row, col, 0)] = (short)hs;
          As[a_addr(row, col, 1)] = (short)ls;
        }
      }
      __syncthreads();
    }
  }

  // ---------- Phase 4: readout ----------------------------------------------
  if (g < TB) {
    const int elem = g;          // 0..7
    const int c = og * 4;        // 4 channels per thread
    float xv[NN][4];
    #pragma unroll
    for (int n = 0; n < NN; ++n) {
      const int row = elem * 16 + n;
      const ushort4 uh = *(const ushort4*)(As + a_addr(row, c, 0));
      const ushort4 ul = *(const ushort4*)(As + a_addr(row, c, 1));
      xv[n][0] = bf2f(uh.x) + bf2f(ul.x);
      xv[n][1] = bf2f(uh.y) + bf2f(ul.y);
      xv[n][2] = bf2f(uh.z) + bf2f(ul.z);
      xv[n][3] = bf2f(uh.w) + bf2f(ul.w);
    }
    #pragma unroll
    for (int j = 0; j < NJ; ++j) {
      const F4 wa = *(const F4*)(Wo + j * 256 + c);
      const F4 wb = *(const F4*)(Wo + j * 256 + 128 + c);
      const float* xa = xv[JM0[j]];
      const float* xb = xv[JM1[j]];
      float p = xa[0]*wa.x + xa[1]*wa.y + xa[2]*wa.z + xa[3]*wa.w
              + xb[0]*wb.x + xb[1]*wb.y + xb[2]*wb.z + xb[3]*wb.w;
      p += __shfl_xor(p, 16);
      p += __shfl_xor(p, 8);
      p += __shfl_xor(p, 4);
      p += __shfl_xor(p, 2);
      p += __shfl_xor(p, 1);
      if (og == 0) out[(b0 + elem) * NJ + j] = p + bo[j];
    }
  }
}

extern "C" void kernel_launch(void* const* d_in, const int* in_sizes, int n_in,
                              void* d_out, int out_size, void* d_ws, size_t ws_size,
                              hipStream_t stream) {
  const float* obs = (const float*)d_in[0];
  const float* W1  = (const float*)d_in[1];
  const float* b1  = (const float*)d_in[2];
  const float* W2  = (const float*)d_in[3];
  const float* b2  = (const float*)d_in[4];
  const float* Wm  = (const float*)d_in[5];
  const float* bm  = (const float*)d_in[6];
  const float* Wo  = (const float*)d_in[7];
  const float* bo  = (const float*)d_in[8];
  float* out = (float*)d_out;

  const int B = in_sizes[0] / OBSD;   // 16384
  const int nblk = B / TB;            // 2048

  // pre-pass: split Wmsg into bf16 hi/lo, frag-swizzled (exactly 1 MB in d_ws)
  prep_wm<<<1024, 256, 0, stream>>>(Wm, (unsigned*)d_ws);
  gnn_fused<<<nblk, NTHR, 0, stream>>>(obs, W1, b1, W2, b2, bm, Wo, bo,
                                       (const float*)d_ws, out);
}

// Round 14
// 716.757 us; speedup vs baseline: 1.4436x; 1.0123x over previous
//
#include <hip/hip_runtime.h>
#include <math.h>

#define NN   13
#define HH   128
#define NL   8
#define NJ   17
#define OBSD 348
#define DMAX 33
#define TB   8
#define NTHR 1024
#define ASTRIDE 256   // shorts per A row = 512 B; unit-swizzled (R8/R11-validated)
#define HSTRIDE 128   // same row viewed as fp32

// FEAT_IDX table (13 x 33), pad = -1
__constant__ int c_feat[NN * DMAX] = {
  0,1,2,3,4,22,23,24,25,26,27,45,46,47,48,49,50,51,52,53,54,175,176,177,178,179,180,270,271,272,273,274,275,
  5,6,28,29,55,56,57,58,59,60,61,62,63,64,181,182,183,184,185,186,276,277,278,279,280,281,-1,-1,-1,-1,-1,-1,-1,
  7,30,65,66,67,68,69,70,71,72,73,74,187,188,189,190,191,192,253,254,255,282,283,284,285,286,287,-1,-1,-1,-1,-1,-1,
  8,9,10,11,31,32,33,34,75,76,77,78,79,80,81,82,83,84,193,194,195,196,197,198,256,257,258,288,289,290,291,292,293,
  11,34,85,86,87,88,89,90,91,92,93,94,199,200,201,202,203,204,259,294,295,296,297,298,299,-1,-1,-1,-1,-1,-1,-1,-1,
  95,96,97,98,99,100,101,102,103,104,205,206,207,208,209,210,300,301,302,303,304,305,-1,-1,-1,-1,-1,-1,-1,-1,-1,-1,-1,
  12,13,14,15,35,36,37,38,105,106,107,108,109,110,111,112,113,114,211,212,213,214,215,216,260,261,262,306,307,308,309,310,311,
  15,38,115,116,117,118,119,120,121,122,123,124,217,218,219,220,221,222,263,312,313,314,315,316,317,-1,-1,-1,-1,-1,-1,-1,-1,
  125,126,127,128,129,130,131,132,133,134,223,224,225,226,227,228,318,319,320,321,322,323,-1,-1,-1,-1,-1,-1,-1,-1,-1,-1,-1,
  16,17,18,39,40,41,135,136,137,138,139,140,141,142,143,144,229,230,231,232,233,234,264,265,324,325,326,327,328,329,-1,-1,-1,
  18,41,145,146,147,148,149,150,151,152,153,154,235,236,237,238,239,240,266,330,331,332,333,334,335,-1,-1,-1,-1,-1,-1,-1,-1,
  19,20,21,42,43,44,155,156,157,158,159,160,161,162,163,164,241,242,243,244,245,246,267,268,336,337,338,339,340,341,-1,-1,-1,
  21,44,165,166,167,168,169,170,171,172,173,174,247,248,249,250,251,252,269,342,343,344,345,346,347,-1,-1,-1,-1,-1,-1,-1,-1
};

__device__ constexpr int ADJ[NN][3] = {
  {1,9,11},{0,2,0},{1,3,6},{2,4,0},{3,5,0},{4,0,0},{2,7,0},
  {6,8,0},{7,0,0},{0,10,0},{9,0,0},{0,12,0},{11,0,0}
};
__device__ constexpr int DEG[NN] = {3,2,3,2,2,1,2,2,1,2,1,2,1};
__device__ constexpr int JM0[NJ] = {1,1,1,2,2,2,3,2,2,2,6,0,0,9,0,0,11};
__device__ constexpr int JM1[NJ] = {2,2,2,3,3,3,4,6,6,6,7,9,9,10,11,11,12};

typedef float4 F4;
using s8v    = __attribute__((ext_vector_type(8)))  short;   // 8 bf16 (4 VGPR)
using f32x16 = __attribute__((ext_vector_type(16))) float;   // MFMA 32x32 C/D

// elu: for v<=0, __expf(v)-1 ~1e-7 abs err — invisible vs 0.0625 floor (R11-validated)
__device__ __forceinline__ float elu1(float v) {
  return v > 0.0f ? v : (__expf(v) - 1.0f);
}

__device__ __forceinline__ unsigned short bf16r(float v) {   // RNE (prep only)
  unsigned u = __float_as_uint(v);
  unsigned r = u + 0x7FFFu + ((u >> 16) & 1u);
  return (unsigned short)(r >> 16);
}
__device__ __forceinline__ float bf2f(unsigned short s) {
  return __uint_as_float(((unsigned)s) << 16);
}

// TRUNCATION split (hot path): hi = top 16 bits, lo = trunc(v - hi).
// Combined representation error ~2^-16 rel (lo absorbs hi's trunc residual)
// — vs 2^-18 for RNE+RNE; both invisible at this problem's tolerance.
// 4 VALU vs ~10 for the RNE pair.
__device__ __forceinline__ void bfsplit(float v, short &hs, short &ls) {
  unsigned u = __float_as_uint(v);
  hs = (short)(u >> 16);
  float hi = __uint_as_float(u & 0xFFFF0000u);
  ls = (short)(__float_as_uint(v - hi) >> 16);
}

// A-plane LDS addressing (R8/R11-validated): phys_unit = (2*oct+half+row)&31
__device__ __forceinline__ int a_addr(int row, int col, int half) {
  const int u = (2 * (col >> 3) + half + row) & 31;
  return row * ASTRIDE + u * 8 + (col & 7);
}

// ---------------- pre-pass: split+swizzle Wmsg into frag-linear order -------
// (verbatim R6/R10/R11/R13 — validated; keeps RNE split)
__global__ void prep_wm(const float* __restrict__ Wm, unsigned* __restrict__ ws) {
  int i = blockIdx.x * 256 + threadIdx.x;      // 0 .. 262143
  int j2   = i & 3;
  int lane = (i >> 2) & 63;
  int nt   = (i >> 8) & 3;
  int kind = (i >> 10) & 3;
  int ks   = (i >> 12) & 7;
  int l    = i >> 15;                          // 0..7
  int k = ks * 16 + ((lane >> 5) * 8) + 2 * j2;
  int n = nt * 32 + (lane & 31);
  int rbase = (kind >= 2) ? 128 : 0;           // bottom half of Wmsg rows = agg part
  float v0 = Wm[((l * 256) + rbase + k) * HH + n];
  float v1 = Wm[((l * 256) + rbase + k + 1) * HH + n];
  unsigned short a, b;
  if ((kind & 1) == 0) { a = bf16r(v0); b = bf16r(v1); }
  else {
    a = bf16r(v0 - bf2f(bf16r(v0)));
    b = bf16r(v1 - bf2f(bf16r(v1)));
  }
  ws[i] = (unsigned)a | ((unsigned)b << 16);
}

// ---------------- main fused kernel (1024 thr, ONE block/CU, 1 tile/wave) ---
__global__ __launch_bounds__(NTHR, 4)
void gnn_fused(const float* __restrict__ obs,
               const float* __restrict__ W1, const float* __restrict__ b1,
               const float* __restrict__ W2, const float* __restrict__ b2,
               const float* __restrict__ bm,
               const float* __restrict__ Wo, const float* __restrict__ bo,
               const float* __restrict__ wmsw,   // pre-swizzled Wmsg
               float* __restrict__ out)
{
  // A-planes: x state, 128 rows (elem*16+node), swizzled 16B units (hi|lo)
  __shared__ short As[128 * ASTRIDE];      // 65536 B ; aliased as fp32 h scratch
  __shared__ float Bb[2][8192];            // 2 x 32 KB (ks-PAIR) ping-pong -> 131072 B

  const int t    = threadIdx.x;
  const int wid  = t >> 6;        // wave 0..15
  const int mq   = wid >> 2;      // m-tile 0..3: rows mq*32 .. mq*32+31
  const int nq   = wid & 3;       // n-quarter 0..3: cols nq*32 .. nq*32+31
  const int lane = t & 63;
  const int l31  = lane & 31;
  const int lh   = lane >> 5;     // k-half within frag / row-group bit in C
  const bool h1  = (lh == 1);
  const int g    = t >> 5;        // 32-thread group 0..31 (VALU phases)
  const int og   = t & 31;
  const int o0   = og << 2;
  const int b0   = blockIdx.x * TB;

  const F4* wsrc4 = (const F4*)wmsw;
  float* hsc = (float*)As;        // h scratch (row stride HSTRIDE floats)
  F4* bufA = (F4*)Bb;             // 2048 F4 each
  F4* bufB = ((F4*)Bb) + 2048;
  float* xnb = Bb[1];             // xn gather scratch (3744 floats < 8192)

  // ---------- Phase 0: zero pad rows; gather xn ----------
  for (int i = t; i < 24 * HSTRIDE; i += NTHR) {   // rows elem*16+{13,14,15}
    int pr = i / HSTRIDE, off = i % HSTRIDE;
    int row = (pr / 3) * 16 + 13 + (pr % 3);
    ((int*)As)[row * HSTRIDE + off] = 0;           // whole row -> swizzle-safe
  }
  for (int i = t; i < TB * NN * DMAX; i += NTHR) {
    int d  = i % DMAX;
    int r  = i / DMAX;
    int nn = r % NN;
    int bb = r / NN;
    int fi = c_feat[nn * DMAX + d];
    float v = (fi >= 0) ? obs[(b0 + bb) * OBSD + fi] : 0.0f;
    xnb[(bb * NN + nn) * 36 + d] = v;
  }
  __syncthreads();

  // ---------- Phase 1 (VALU): h = elu(xn @ W1 + b1) -> hsc fp32 -------------
  {
    const int n  = g >> 1;         // 0..15, active < 13
    const int q0 = (g & 1) * 4;    // 4 elems per group
    if (n < NN) {
      float acc[4][4];
      const F4 bv = *(const F4*)(b1 + n * HH + o0);
      #pragma unroll
      for (int q = 0; q < 4; ++q) { acc[q][0]=bv.x; acc[q][1]=bv.y; acc[q][2]=bv.z; acc[q][3]=bv.w; }
      #pragma unroll 3
      for (int k = 0; k < DMAX; ++k) {
        const F4 w = *(const F4*)(W1 + (n * DMAX + k) * HH + o0);
        #pragma unroll
        for (int q = 0; q < 4; ++q) {
          const float xv = xnb[((q0 + q) * NN + n) * 36 + k];
          acc[q][0] += xv * w.x; acc[q][1] += xv * w.y;
          acc[q][2] += xv * w.z; acc[q][3] += xv * w.w;
        }
      }
      #pragma unroll
      for (int q = 0; q < 4; ++q) {
        F4 h;
        h.x = elu1(acc[q][0]); h.y = elu1(acc[q][1]);
        h.z = elu1(acc[q][2]); h.w = elu1(acc[q][3]);
        *(F4*)&hsc[((q0 + q) * 16 + n) * HSTRIDE + o0] = h;
      }
    }
  }
  __syncthreads();

  // ---------- Phase 2 (VALU): x = h @ W2 + b2 -> regs, then split-store ------
  float xacc[4][4];
  {
    const int n  = g >> 1;
    const int q0 = (g & 1) * 4;
    if (n < NN) {
      const F4 bv = *(const F4*)(b2 + n * HH + o0);
      #pragma unroll
      for (int q = 0; q < 4; ++q) {
        xacc[q][0]=bv.x; xacc[q][1]=bv.y; xacc[q][2]=bv.z; xacc[q][3]=bv.w;
      }
      #pragma unroll 2
      for (int k4 = 0; k4 < 32; ++k4) {
        const F4 w0 = *(const F4*)(W2 + (n * HH + k4*4 + 0) * HH + o0);
        const F4 w1 = *(const F4*)(W2 + (n * HH + k4*4 + 1) * HH + o0);
        const F4 w2 = *(const F4*)(W2 + (n * HH + k4*4 + 2) * HH + o0);
        const F4 w3 = *(const F4*)(W2 + (n * HH + k4*4 + 3) * HH + o0);
        #pragma unroll
        for (int q = 0; q < 4; ++q) {
          const F4 hv = *(const F4*)&hsc[((q0 + q) * 16 + n) * HSTRIDE + k4 * 4];
          xacc[q][0] += hv.x*w0.x + hv.y*w1.x + hv.z*w2.x + hv.w*w3.x;
          xacc[q][1] += hv.x*w0.y + hv.y*w1.y + hv.z*w2.y + hv.w*w3.y;
          xacc[q][2] += hv.x*w0.z + hv.y*w1.z + hv.z*w2.z + hv.w*w3.z;
          xacc[q][3] += hv.x*w0.w + hv.y*w1.w + hv.z*w2.w + hv.w*w3.w;
        }
      }
    }
  }
  __syncthreads();   // all h reads done; safe to overwrite As with x planes
  {
    const int n  = g >> 1;
    const int q0 = (g & 1) * 4;
    if (n < NN) {
      #pragma unroll
      for (int q = 0; q < 4; ++q) {
        #pragma unroll
        for (int cc = 0; cc < 4; ++cc) {
          short hs, ls;
          bfsplit(xacc[q][cc], hs, ls);
          const int row = (q0 + q) * 16 + n, col = o0 + cc;
          As[a_addr(row, col, 0)] = hs;
          As[a_addr(row, col, 1)] = ls;
        }
      }
    }
  }
  __syncthreads();

  // ---------- Phase 3: 8 MFMA layers (ks-PAIR chunks: 4+1 barriers/layer) ----
  {
    // prologue: stage pair 0 (2048 F4, two per thread)
    bufA[t] = wsrc4[t]; bufA[t + 1024] = wsrc4[t + 1024];
    __syncthreads();

    #pragma unroll 1
    for (int l = 0; l < NL; ++l) {
      f32x16 aT, aB;
      #pragma unroll
      for (int r = 0; r < 16; ++r) { aT[r] = 0.f; aB[r] = 0.f; }

      #pragma unroll 1
      for (int kp = 0; kp < 4; ++kp) {
        const int gpc = l * 4 + kp;          // global pair index 0..31
        F4* cur = (gpc & 1) ? bufB : bufA;
        F4* nxt = (gpc & 1) ? bufA : bufB;

        F4 r0, r1;
        const bool more = (gpc < NL * 4 - 1);
        if (more) {
          const F4* s = wsrc4 + (size_t)(gpc + 1) * 2048;
          r0 = s[t]; r1 = s[t + 1024];
        }

        #pragma unroll
        for (int kk = 0; kk < 2; ++kk) {
          const int ks = kp * 2 + kk;
          // 16 KB sub-chunk = 8192 shorts
          const short* bb = ((const short*)cur) + kk * 8192;

          s8v ah, al;
          {
            const int row = mq * 32 + l31;
            const int p = 2 * ks + lh;         // oct index 0..15
            ah = *(const s8v*)(As + row * ASTRIDE + (((2 * p + row) & 31) * 8));
            al = *(const s8v*)(As + row * ASTRIDE + (((2 * p + 1 + row) & 31) * 8));
          }
          const s8v bth = *(const s8v*)(bb + ((0 * 4 + nq) * 64 + lane) * 8);
          const s8v btl = *(const s8v*)(bb + ((1 * 4 + nq) * 64 + lane) * 8);
          const s8v bbh = *(const s8v*)(bb + ((2 * 4 + nq) * 64 + lane) * 8);
          const s8v bbl = *(const s8v*)(bb + ((3 * 4 + nq) * 64 + lane) * 8);

          aT = __builtin_amdgcn_mfma_f32_32x32x16_bf16(ah, bth, aT, 0, 0, 0);
          aT = __builtin_amdgcn_mfma_f32_32x32x16_bf16(ah, btl, aT, 0, 0, 0);
          aT = __builtin_amdgcn_mfma_f32_32x32x16_bf16(al, bth, aT, 0, 0, 0);
          aB = __builtin_amdgcn_mfma_f32_32x32x16_bf16(ah, bbh, aB, 0, 0, 0);
          aB = __builtin_amdgcn_mfma_f32_32x32x16_bf16(ah, bbl, aB, 0, 0, 0);
          aB = __builtin_amdgcn_mfma_f32_32x32x16_bf16(al, bbh, aB, 0, 0, 0);
        }

        if (more) { nxt[t] = r0; nxt[t + 1024] = r1; }
        __syncthreads();   // publishes nxt; guards cur reuse and A-row overwrite
      }

      // epilogue: x_new = elu(Y_top + N*Y_bot + bias) ; trunc-split-store to As
      {
        const int col  = nq * 32 + l31;
        const float bias = bm[l * HH + col];
        float cb[16], sw[16];
        #pragma unroll
        for (int r = 0; r < 16; ++r) { cb[r] = aB[r]; sw[r] = __shfl_xor(cb[r], 32); }

        #pragma unroll
        for (int r = 0; r < 16; ++r) {
          const int p  = (r & 3) + 8 * (r >> 2);
          const int n0 = p & 15;            // node for lane-half 0 (always < 13)
          const int n1 = n0 + 4;            // node for lane-half 1 (may be pad)
          const int es = p >> 4;
          #define SRCV(np)                                                \
            ({ const int rl = (es << 4) + (np);                           \
               const int hp = (rl >> 2) & 1;                              \
               const int pp = rl - 4 * hp;                                \
               const int rp = (pp & 3) + 4 * (pp >> 3);                   \
               (hp == 1) ? (h1 ? cb[rp] : sw[rp])                         \
                         : (h1 ? sw[rp] : cb[rp]); })
          float a0 = SRCV(ADJ[n0][0]);
          if (DEG[n0] > 1) a0 += SRCV(ADJ[n0][1]);
          if (DEG[n0] > 2) a0 += SRCV(ADJ[n0][2]);
          float a1 = 0.f;
          if (n1 < NN) {
            a1 = SRCV(ADJ[n1][0]);
            if (DEG[n1] > 1) a1 += SRCV(ADJ[n1][1]);
            if (DEG[n1] > 2) a1 += SRCV(ADJ[n1][2]);
          }
          #undef SRCV
          const float agg = h1 ? a1 : a0;
          const float tot = aT[r] + agg + bias;
          float xv = elu1(tot);
          if (n1 >= NN) xv = h1 ? 0.f : xv;     // pad rows stay zero (stored)
          short hs, ls;
          bfsplit(xv, hs, ls);
          const int row = mq * 32 + p + 4 * lh;
          As[a_addr(row, col, 0)] = hs;
          As[a_addr(row, col, 1)] = ls;
        }
      }
      __syncthreads();
    }
  }

  // ---------- Phase 4: readout ----------------------------------------------
  if (g < TB) {
    const int elem = g;          // 0..7
    const int c = og * 4;        // 4 channels per thread
    float xv[NN][4];
    #pragma unroll
    for (int n = 0; n < NN; ++n) {
      const int row = elem * 16 + n;
      const ushort4 uh = *(const ushort4*)(As + a_addr(row, c, 0));
      const ushort4 ul = *(const ushort4*)(As + a_addr(row, c, 1));
      xv[n][0] = bf2f(uh.x) + bf2f(ul.x);
      xv[n][1] = bf2f(uh.y) + bf2f(ul.y);
      xv[n][2] = bf2f(uh.z) + bf2f(ul.z);
      xv[n][3] = bf2f(uh.w) + bf2f(ul.w);
    }
    #pragma unroll
    for (int j = 0; j < NJ; ++j) {
      const F4 wa = *(const F4*)(Wo + j * 256 + c);
      const F4 wb = *(const F4*)(Wo + j * 256 + 128 + c);
      const float* xa = xv[JM0[j]];
      const float* xb = xv[JM1[j]];
      float p = xa[0]*wa.x + xa[1]*wa.y + xa[2]*wa.z + xa[3]*wa.w
              + xb[0]*wb.x + xb[1]*wb.y + xb[2]*wb.z + xb[3]*wb.w;
      p += __shfl_xor(p, 16);
      p += __shfl_xor(p, 8);
      p += __shfl_xor(p, 4);
      p += __shfl_xor(p, 2);
      p += __shfl_xor(p, 1);
      if (og == 0) out[(b0 + elem) * NJ + j] = p + bo[j];
    }
  }
}

extern "C" void kernel_launch(void* const* d_in, const int* in_sizes, int n_in,
                              void* d_out, int out_size, void* d_ws, size_t ws_size,
                              hipStream_t stream) {
  const float* obs = (const float*)d_in[0];
  const float* W1  = (const float*)d_in[1];
  const float* b1  = (const float*)d_in[2];
  const float* W2  = (const float*)d_in[3];
  const float* b2  = (const float*)d_in[4];
  const float* Wm  = (const float*)d_in[5];
  const float* bm  = (const float*)d_in[6];
  const float* Wo  = (const float*)d_in[7];
  const float* bo  = (const float*)d_in[8];
  float* out = (float*)d_out;

  const int B = in_sizes[0] / OBSD;   // 16384
  const int nblk = B / TB;            // 2048

  // pre-pass: split Wmsg into bf16 hi/lo, frag-swizzled (exactly 1 MB in d_ws)
  prep_wm<<<1024, 256, 0, stream>>>(Wm, (unsigned*)d_ws);
  gnn_fused<<<nblk, NTHR, 0, stream>>>(obs, W1, b1, W2, b2, bm, Wo, bo,
                                       (const float*)d_ws, out);
}

// Round 15
// 623.363 us; speedup vs baseline: 1.6599x; 1.1498x over previous
//
#include <hip/hip_runtime.h>
#include <math.h>

#define NN   13
#define HH   128
#define NL   8
#define NJ   17
#define OBSD 348
#define DMAX 33
#define TB   8
#define NTHR 1024
#define ASTRIDE 256   // shorts per A row = 512 B; unit-swizzled (R8/R11-validated)
#define HSTRIDE 128   // same row viewed as fp32

// FEAT_IDX table (13 x 33), pad = -1
__constant__ int c_feat[NN * DMAX] = {
  0,1,2,3,4,22,23,24,25,26,27,45,46,47,48,49,50,51,52,53,54,175,176,177,178,179,180,270,271,272,273,274,275,
  5,6,28,29,55,56,57,58,59,60,61,62,63,64,181,182,183,184,185,186,276,277,278,279,280,281,-1,-1,-1,-1,-1,-1,-1,
  7,30,65,66,67,68,69,70,71,72,73,74,187,188,189,190,191,192,253,254,255,282,283,284,285,286,287,-1,-1,-1,-1,-1,-1,
  8,9,10,11,31,32,33,34,75,76,77,78,79,80,81,82,83,84,193,194,195,196,197,198,256,257,258,288,289,290,291,292,293,
  11,34,85,86,87,88,89,90,91,92,93,94,199,200,201,202,203,204,259,294,295,296,297,298,299,-1,-1,-1,-1,-1,-1,-1,-1,
  95,96,97,98,99,100,101,102,103,104,205,206,207,208,209,210,300,301,302,303,304,305,-1,-1,-1,-1,-1,-1,-1,-1,-1,-1,-1,
  12,13,14,15,35,36,37,38,105,106,107,108,109,110,111,112,113,114,211,212,213,214,215,216,260,261,262,306,307,308,309,310,311,
  15,38,115,116,117,118,119,120,121,122,123,124,217,218,219,220,221,222,263,312,313,314,315,316,317,-1,-1,-1,-1,-1,-1,-1,-1,
  125,126,127,128,129,130,131,132,133,134,223,224,225,226,227,228,318,319,320,321,322,323,-1,-1,-1,-1,-1,-1,-1,-1,-1,-1,-1,
  16,17,18,39,40,41,135,136,137,138,139,140,141,142,143,144,229,230,231,232,233,234,264,265,324,325,326,327,328,329,-1,-1,-1,
  18,41,145,146,147,148,149,150,151,152,153,154,235,236,237,238,239,240,266,330,331,332,333,334,335,-1,-1,-1,-1,-1,-1,-1,-1,
  19,20,21,42,43,44,155,156,157,158,159,160,161,162,163,164,241,242,243,244,245,246,267,268,336,337,338,339,340,341,-1,-1,-1,
  21,44,165,166,167,168,169,170,171,172,173,174,247,248,249,250,251,252,269,342,343,344,345,346,347,-1,-1,-1,-1,-1,-1,-1,-1
};

__device__ constexpr int ADJ[NN][3] = {
  {1,9,11},{0,2,0},{1,3,6},{2,4,0},{3,5,0},{4,0,0},{2,7,0},
  {6,8,0},{7,0,0},{0,10,0},{9,0,0},{0,12,0},{11,0,0}
};
__device__ constexpr int DEG[NN] = {3,2,3,2,2,1,2,2,1,2,1,2,1};
__device__ constexpr int JM0[NJ] = {1,1,1,2,2,2,3,2,2,2,6,0,0,9,0,0,11};
__device__ constexpr int JM1[NJ] = {2,2,2,3,3,3,4,6,6,6,7,9,9,10,11,11,12};

typedef float4 F4;
using h8v    = __attribute__((ext_vector_type(8))) _Float16;  // 8 fp16 (4 VGPR)
using f32x16 = __attribute__((ext_vector_type(16))) float;    // MFMA 32x32 C/D

// elu: for v<=0, __expf(v)-1 ~1e-7 abs err — invisible vs 0.0625 floor (R11-validated)
__device__ __forceinline__ float elu1(float v) {
  return v > 0.0f ? v : (__expf(v) - 1.0f);
}

// fp16 two-plane split: hi = fp16(v) RNE, lo = fp16(v - hi).
// Combined representation error ~2^-22 rel — far below bf16 3-term.
__device__ __forceinline__ void hsplit(float v, short &hs, short &ls) {
  _Float16 h = (_Float16)v;
  hs = (short)__builtin_bit_cast(unsigned short, h);
  _Float16 lo = (_Float16)(v - (float)h);
  ls = (short)__builtin_bit_cast(unsigned short, lo);
}
__device__ __forceinline__ float h2f(unsigned short s) {
  return (float)__builtin_bit_cast(_Float16, s);
}

// A-plane LDS addressing (R8/R11-validated): phys_unit = (2*oct+half+row)&31
__device__ __forceinline__ int a_addr(int row, int col, int half) {
  const int u = (2 * (col >> 3) + half + row) & 31;
  return row * ASTRIDE + u * 8 + (col & 7);
}

// ---------------- pre-pass: fp16 Wmsg (single plane), frag-linear order -----
// ws u32 layout: [l(8)][ks(8)][kind(2: T,B)][nt(4)][lane(64)][j2(4)]
// value pair: k = ks*16 + (lane>>5)*8 + 2*j2 ; n = nt*32 + (lane&31)
// EXACT size: 8*8*2*4*64*4 = 131072 u32 = 512 KB -> grid 512 x 256
__global__ void prep_wm(const float* __restrict__ Wm, unsigned* __restrict__ ws) {
  int i = blockIdx.x * 256 + threadIdx.x;      // 0 .. 131071
  int j2   = i & 3;
  int lane = (i >> 2) & 63;
  int nt   = (i >> 8) & 3;
  int kind = (i >> 10) & 1;
  int ks   = (i >> 11) & 7;
  int l    = i >> 14;                          // 0..7
  int k = ks * 16 + ((lane >> 5) * 8) + 2 * j2;
  int n = nt * 32 + (lane & 31);
  int rbase = kind ? 128 : 0;                  // bottom half of Wmsg rows = agg part
  float v0 = Wm[((l * 256) + rbase + k) * HH + n];
  float v1 = Wm[((l * 256) + rbase + k + 1) * HH + n];
  _Float16 a = (_Float16)v0, b = (_Float16)v1;  // RNE
  unsigned short ua = __builtin_bit_cast(unsigned short, a);
  unsigned short ub = __builtin_bit_cast(unsigned short, b);
  ws[i] = (unsigned)ua | ((unsigned)ub << 16);
}

// ---------------- main fused kernel (1024 thr, ONE block/CU, 1 tile/wave) ---
__global__ __launch_bounds__(NTHR, 4)
void gnn_fused(const float* __restrict__ obs,
               const float* __restrict__ W1, const float* __restrict__ b1,
               const float* __restrict__ W2, const float* __restrict__ b2,
               const float* __restrict__ bm,
               const float* __restrict__ Wo, const float* __restrict__ bo,
               const float* __restrict__ wmsw,   // pre-swizzled Wmsg (fp16)
               float* __restrict__ out)
{
  // A-planes: x state fp16 hi/lo, 128 rows (elem*16+node), swizzled 16B units
  __shared__ short As[128 * ASTRIDE];      // 65536 B ; aliased as fp32 h scratch
  __shared__ float Bb[2][4096];            // 2 x 16 KB (ks-PAIR fp16) ping-pong -> 98304 B

  const int t    = threadIdx.x;
  const int wid  = t >> 6;        // wave 0..15
  const int mq   = wid >> 2;      // m-tile 0..3: rows mq*32 .. mq*32+31
  const int nq   = wid & 3;       // n-quarter 0..3: cols nq*32 .. nq*32+31
  const int lane = t & 63;
  const int l31  = lane & 31;
  const int lh   = lane >> 5;     // k-half within frag / row-group bit in C
  const bool h1  = (lh == 1);
  const int g    = t >> 5;        // 32-thread group 0..31 (VALU phases)
  const int og   = t & 31;
  const int o0   = og << 2;
  const int b0   = blockIdx.x * TB;

  const F4* wsrc4 = (const F4*)wmsw;
  float* hsc = (float*)As;        // h scratch (row stride HSTRIDE floats)
  F4* bufA = (F4*)Bb;             // 1024 F4 each
  F4* bufB = ((F4*)Bb) + 1024;
  float* xnb = Bb[1];             // xn gather scratch (3744 floats < 4096)

  // ---------- Phase 0: zero pad rows; gather xn ----------
  for (int i = t; i < 24 * HSTRIDE; i += NTHR) {   // rows elem*16+{13,14,15}
    int pr = i / HSTRIDE, off = i % HSTRIDE;
    int row = (pr / 3) * 16 + 13 + (pr % 3);
    ((int*)As)[row * HSTRIDE + off] = 0;           // whole row -> swizzle-safe
  }
  for (int i = t; i < TB * NN * DMAX; i += NTHR) {
    int d  = i % DMAX;
    int r  = i / DMAX;
    int nn = r % NN;
    int bb = r / NN;
    int fi = c_feat[nn * DMAX + d];
    float v = (fi >= 0) ? obs[(b0 + bb) * OBSD + fi] : 0.0f;
    xnb[(bb * NN + nn) * 36 + d] = v;
  }
  __syncthreads();

  // ---------- Phase 1 (VALU): h = elu(xn @ W1 + b1) -> hsc fp32 -------------
  {
    const int n  = g >> 1;         // 0..15, active < 13
    const int q0 = (g & 1) * 4;    // 4 elems per group
    if (n < NN) {
      float acc[4][4];
      const F4 bv = *(const F4*)(b1 + n * HH + o0);
      #pragma unroll
      for (int q = 0; q < 4; ++q) { acc[q][0]=bv.x; acc[q][1]=bv.y; acc[q][2]=bv.z; acc[q][3]=bv.w; }
      #pragma unroll 3
      for (int k = 0; k < DMAX; ++k) {
        const F4 w = *(const F4*)(W1 + (n * DMAX + k) * HH + o0);
        #pragma unroll
        for (int q = 0; q < 4; ++q) {
          const float xv = xnb[((q0 + q) * NN + n) * 36 + k];
          acc[q][0] += xv * w.x; acc[q][1] += xv * w.y;
          acc[q][2] += xv * w.z; acc[q][3] += xv * w.w;
        }
      }
      #pragma unroll
      for (int q = 0; q < 4; ++q) {
        F4 h;
        h.x = elu1(acc[q][0]); h.y = elu1(acc[q][1]);
        h.z = elu1(acc[q][2]); h.w = elu1(acc[q][3]);
        *(F4*)&hsc[((q0 + q) * 16 + n) * HSTRIDE + o0] = h;
      }
    }
  }
  __syncthreads();

  // ---------- Phase 2 (VALU): x = h @ W2 + b2 -> regs, then split-store ------
  float xacc[4][4];
  {
    const int n  = g >> 1;
    const int q0 = (g & 1) * 4;
    if (n < NN) {
      const F4 bv = *(const F4*)(b2 + n * HH + o0);
      #pragma unroll
      for (int q = 0; q < 4; ++q) {
        xacc[q][0]=bv.x; xacc[q][1]=bv.y; xacc[q][2]=bv.z; xacc[q][3]=bv.w;
      }
      #pragma unroll 2
      for (int k4 = 0; k4 < 32; ++k4) {
        const F4 w0 = *(const F4*)(W2 + (n * HH + k4*4 + 0) * HH + o0);
        const F4 w1 = *(const F4*)(W2 + (n * HH + k4*4 + 1) * HH + o0);
        const F4 w2 = *(const F4*)(W2 + (n * HH + k4*4 + 2) * HH + o0);
        const F4 w3 = *(const F4*)(W2 + (n * HH + k4*4 + 3) * HH + o0);
        #pragma unroll
        for (int q = 0; q < 4; ++q) {
          const F4 hv = *(const F4*)&hsc[((q0 + q) * 16 + n) * HSTRIDE + k4 * 4];
          xacc[q][0] += hv.x*w0.x + hv.y*w1.x + hv.z*w2.x + hv.w*w3.x;
          xacc[q][1] += hv.x*w0.y + hv.y*w1.y + hv.z*w2.y + hv.w*w3.y;
          xacc[q][2] += hv.x*w0.z + hv.y*w1.z + hv.z*w2.z + hv.w*w3.z;
          xacc[q][3] += hv.x*w0.w + hv.y*w1.w + hv.z*w2.w + hv.w*w3.w;
        }
      }
    }
  }
  __syncthreads();   // all h reads done; safe to overwrite As with x planes
  {
    const int n  = g >> 1;
    const int q0 = (g & 1) * 4;
    if (n < NN) {
      #pragma unroll
      for (int q = 0; q < 4; ++q) {
        #pragma unroll
        for (int cc = 0; cc < 4; ++cc) {
          short hs, ls;
          hsplit(xacc[q][cc], hs, ls);
          const int row = (q0 + q) * 16 + n, col = o0 + cc;
          As[a_addr(row, col, 0)] = hs;
          As[a_addr(row, col, 1)] = ls;
        }
      }
    }
  }
  __syncthreads();

  // ---------- Phase 3: 8 MFMA layers (fp16 2-term, ks-PAIR chunks) -----------
  {
    // prologue: stage pair 0 (1024 F4, one per thread)
    bufA[t] = wsrc4[t];
    __syncthreads();

    #pragma unroll 1
    for (int l = 0; l < NL; ++l) {
      f32x16 aT, aB;
      #pragma unroll
      for (int r = 0; r < 16; ++r) { aT[r] = 0.f; aB[r] = 0.f; }

      #pragma unroll 1
      for (int kp = 0; kp < 4; ++kp) {
        const int gpc = l * 4 + kp;          // global pair index 0..31
        F4* cur = (gpc & 1) ? bufB : bufA;
        F4* nxt = (gpc & 1) ? bufA : bufB;

        F4 r0;
        const bool more = (gpc < NL * 4 - 1);
        if (more) r0 = wsrc4[(size_t)(gpc + 1) * 1024 + t];

        #pragma unroll
        for (int kk = 0; kk < 2; ++kk) {
          const int ks = kp * 2 + kk;
          // 8 KB sub-chunk = 4096 shorts
          const short* bb = ((const short*)cur) + kk * 4096;

          h8v ah, al;
          {
            const int row = mq * 32 + l31;
            const int p = 2 * ks + lh;         // oct index 0..15
            ah = *(const h8v*)(As + row * ASTRIDE + (((2 * p + row) & 31) * 8));
            al = *(const h8v*)(As + row * ASTRIDE + (((2 * p + 1 + row) & 31) * 8));
          }
          const h8v bth = *(const h8v*)(bb + ((0 * 4 + nq) * 64 + lane) * 8);
          const h8v bbh = *(const h8v*)(bb + ((1 * 4 + nq) * 64 + lane) * 8);

          aT = __builtin_amdgcn_mfma_f32_32x32x16_f16(ah, bth, aT, 0, 0, 0);
          aT = __builtin_amdgcn_mfma_f32_32x32x16_f16(al, bth, aT, 0, 0, 0);
          aB = __builtin_amdgcn_mfma_f32_32x32x16_f16(ah, bbh, aB, 0, 0, 0);
          aB = __builtin_amdgcn_mfma_f32_32x32x16_f16(al, bbh, aB, 0, 0, 0);
        }

        if (more) nxt[t] = r0;
        __syncthreads();   // publishes nxt; guards cur reuse and A-row overwrite
      }

      // epilogue: x_new = elu(Y_top + N*Y_bot + bias) ; fp16-split-store to As
      {
        const int col  = nq * 32 + l31;
        const float bias = bm[l * HH + col];
        float cb[16], sw[16];
        #pragma unroll
        for (int r = 0; r < 16; ++r) { cb[r] = aB[r]; sw[r] = __shfl_xor(cb[r], 32); }

        #pragma unroll
        for (int r = 0; r < 16; ++r) {
          const int p  = (r & 3) + 8 * (r >> 2);
          const int n0 = p & 15;            // node for lane-half 0 (always < 13)
          const int n1 = n0 + 4;            // node for lane-half 1 (may be pad)
          const int es = p >> 4;
          #define SRCV(np)                                                \
            ({ const int rl = (es << 4) + (np);                           \
               const int hp = (rl >> 2) & 1;                              \
               const int pp = rl - 4 * hp;                                \
               const int rp = (pp & 3) + 4 * (pp >> 3);                   \
               (hp == 1) ? (h1 ? cb[rp] : sw[rp])                         \
                         : (h1 ? sw[rp] : cb[rp]); })
          float a0 = SRCV(ADJ[n0][0]);
          if (DEG[n0] > 1) a0 += SRCV(ADJ[n0][1]);
          if (DEG[n0] > 2) a0 += SRCV(ADJ[n0][2]);
          float a1 = 0.f;
          if (n1 < NN) {
            a1 = SRCV(ADJ[n1][0]);
            if (DEG[n1] > 1) a1 += SRCV(ADJ[n1][1]);
            if (DEG[n1] > 2) a1 += SRCV(ADJ[n1][2]);
          }
          #undef SRCV
          const float agg = h1 ? a1 : a0;
          const float tot = aT[r] + agg + bias;
          float xv = elu1(tot);
          if (n1 >= NN) xv = h1 ? 0.f : xv;     // pad rows stay zero (stored)
          short hs, ls;
          hsplit(xv, hs, ls);
          const int row = mq * 32 + p + 4 * lh;
          As[a_addr(row, col, 0)] = hs;
          As[a_addr(row, col, 1)] = ls;
        }
      }
      __syncthreads();
    }
  }

  // ---------- Phase 4: readout ----------------------------------------------
  if (g < TB) {
    const int elem = g;          // 0..7
    const int c = og * 4;        // 4 channels per thread
    float xv[NN][4];
    #pragma unroll
    for (int n = 0; n < NN; ++n) {
      const int row = elem * 16 + n;
      const ushort4 uh = *(const ushort4*)(As + a_addr(row, c, 0));
      const ushort4 ul = *(const ushort4*)(As + a_addr(row, c, 1));
      xv[n][0] = h2f(uh.x) + h2f(ul.x);
      xv[n][1] = h2f(uh.y) + h2f(ul.y);
      xv[n][2] = h2f(uh.z) + h2f(ul.z);
      xv[n][3] = h2f(uh.w) + h2f(ul.w);
    }
    #pragma unroll
    for (int j = 0; j < NJ; ++j) {
      const F4 wa = *(const F4*)(Wo + j * 256 + c);
      const F4 wb = *(const F4*)(Wo + j * 256 + 128 + c);
      const float* xa = xv[JM0[j]];
      const float* xb = xv[JM1[j]];
      float p = xa[0]*wa.x + xa[1]*wa.y + xa[2]*wa.z + xa[3]*wa.w
              + xb[0]*wb.x + xb[1]*wb.y + xb[2]*wb.z + xb[3]*wb.w;
      p += __shfl_xor(p, 16);
      p += __shfl_xor(p, 8);
      p += __shfl_xor(p, 4);
      p += __shfl_xor(p, 2);
      p += __shfl_xor(p, 1);
      if (og == 0) out[(b0 + elem) * NJ + j] = p + bo[j];
    }
  }
}

extern "C" void kernel_launch(void* const* d_in, const int* in_sizes, int n_in,
                              void* d_out, int out_size, void* d_ws, size_t ws_size,
                              hipStream_t stream) {
  const float* obs = (const float*)d_in[0];
  const float* W1  = (const float*)d_in[1];
  const float* b1  = (const float*)d_in[2];
  const float* W2  = (const float*)d_in[3];
  const float* b2  = (const float*)d_in[4];
  const float* Wm  = (const float*)d_in[5];
  const float* bm  = (const float*)d_in[6];
  const float* Wo  = (const float*)d_in[7];
  const float* bo  = (const float*)d_in[8];
  float* out = (float*)d_out;

  const int B = in_sizes[0] / OBSD;   // 16384
  const int nblk = B / TB;            // 2048

  // pre-pass: fp16 Wmsg, frag-swizzled (exactly 512 KB in d_ws)
  prep_wm<<<512, 256, 0, stream>>>(Wm, (unsigned*)d_ws);
  gnn_fused<<<nblk, NTHR, 0, stream>>>(obs, W1, b1, W2, b2, bm, Wo, bo,
                                       (const float*)d_ws, out);
}